// Round 6
// baseline (330.503 us; speedup 1.0000x reference)
//
#include <hip/hip_runtime.h>
#include <hip/hip_bf16.h>

using u16 = unsigned short;
typedef __bf16 bf16x8 __attribute__((ext_vector_type(8)));
typedef float f32x4 __attribute__((ext_vector_type(4)));

// B=4, S=512, KV=4096, D=1024, H=16, HD=64
#define SB 4
#define SS 512
#define SKV 4096
#define SD 1024
#define SH 16
#define SHD 64
#define NSPLIT 4
#define NROWS 32768   // B*H*S
#define QSCALE 0.18033688011112042f   // 0.125 * log2(e): softmax in base-2 domain

__device__ inline u16 f2bf(float f){
  __hip_bfloat16 h = __float2bfloat16(f);
  return __builtin_bit_cast(u16, h);
}

__device__ inline bf16x8 ld_frag_g(const u16* p){
  uint4 v = *reinterpret_cast<const uint4*>(p);
  return __builtin_bit_cast(bf16x8, v);
}

__device__ inline bf16x8 ld_frag_lds(const char* base, int ob){
  uint4 v = *reinterpret_cast<const uint4*>(base + ob);
  return __builtin_bit_cast(bf16x8, v);
}

// async global->LDS, 16B per lane; dest = wave-uniform base + lane*16
__device__ inline void gload_lds16(const u16* g, u16* l){
  __builtin_amdgcn_global_load_lds(
      (const __attribute__((address_space(1))) void*)g,
      (__attribute__((address_space(3))) void*)l, 16, 0, 0);
}

// ---------- f32 -> bf16 cast ----------
__global__ __launch_bounds__(256) void cast_kernel(const float* __restrict__ src,
                                                   u16* __restrict__ dst, int n4){
  int i = blockIdx.x * 256 + threadIdx.x;
  if (i < n4){
    float4 f = reinterpret_cast<const float4*>(src)[i];
    ushort4 u;
    u.x = f2bf(f.x); u.y = f2bf(f.y); u.z = f2bf(f.z); u.w = f2bf(f.w);
    reinterpret_cast<ushort4*>(dst)[i] = u;
  }
}

// ---------- GEMM: C[M,N] = A[M,K] * W[N,K]^T (+bias), K=N=1024 ----------
// global_load_lds width=16 with FRAGMENT-LAYOUT LDS (pre-permuted global
// source, linear LDS dest — m173 pattern): fragment f=(g,kk) of the 128x64
// tile lives at byte offset f*1024 + lane*16, so every ds_read_b128 is
// lane*16-contiguous => conflict-free. No swizzle anywhere (rule #21).
enum { MODE_Q = 0, MODE_K = 1, MODE_V = 2, MODE_OUT = 3 };

template<int MODE>
__global__ __launch_bounds__(256) void gemm_bt(const u16* __restrict__ A,
                                               const u16* __restrict__ W,
                                               const float* __restrict__ bias,
                                               float* __restrict__ outF,
                                               u16* __restrict__ outB)
{
  __shared__ u16 As[128*64];     // 16 fragments x 1KB
  __shared__ u16 Bs[128*64];
  const int tid  = threadIdx.x;
  const int lane = tid & 63;
  const int wid  = tid >> 6;
  const int l15  = lane & 15;
  const int lhi  = lane >> 4;
  const int wm   = (wid >> 1) * 64;
  const int wn   = (wid & 1) * 64;
  const long rowBase = (long)blockIdx.x * 128;
  const long colBase = (long)blockIdx.y * 128;

  // per-thread global source bases for the 4 A/W staging instrs:
  // instr i stages fragment f = i*4+wid: rows (f>>1)*16+l15, k = (f&1)*32+lhi*8
  const u16* gaB[4]; const u16* gwB[4];
#pragma unroll
  for (int i = 0; i < 4; i++){
    int f = i * 4 + wid, g = f >> 1, kk = f & 1;
    gaB[i] = A + (rowBase + g * 16 + l15) * 1024 + kk * 32 + lhi * 8;
    gwB[i] = W + (colBase + g * 16 + l15) * 1024 + kk * 32 + lhi * 8;
  }

  f32x4 acc[4][4];
#pragma unroll
  for (int i = 0; i < 4; i++)
#pragma unroll
    for (int j = 0; j < 4; j++)
      acc[i][j] = (f32x4){0.f, 0.f, 0.f, 0.f};

  for (int kt = 0; kt < 16; ++kt){
    __syncthreads();                         // readers of previous tile done
#pragma unroll
    for (int i = 0; i < 4; i++){
      int f = i * 4 + wid;
      gload_lds16(gaB[i] + kt * 64, As + f * 512);
      gload_lds16(gwB[i] + kt * 64, Bs + f * 512);
    }
    __syncthreads();                         // compiler drains vmcnt(0) first
#pragma unroll
    for (int kk = 0; kk < 2; kk++){
      bf16x8 af[4], bfr[4];
#pragma unroll
      for (int mi = 0; mi < 4; mi++){
        int fA = ((wm >> 4) + mi) * 2 + kk;  // wm/16 = (wid>>1)*4
        af[mi] = ld_frag_lds(reinterpret_cast<const char*>(As), fA * 1024 + lane * 16);
      }
#pragma unroll
      for (int ni = 0; ni < 4; ni++){
        int fB = ((wn >> 4) + ni) * 2 + kk;
        bfr[ni] = ld_frag_lds(reinterpret_cast<const char*>(Bs), fB * 1024 + lane * 16);
      }
#pragma unroll
      for (int mi = 0; mi < 4; mi++)
#pragma unroll
        for (int ni = 0; ni < 4; ni++)
          acc[mi][ni] = __builtin_amdgcn_mfma_f32_16x16x32_bf16(af[mi], bfr[ni], acc[mi][ni], 0, 0, 0);
    }
  }

#pragma unroll
  for (int mi = 0; mi < 4; mi++){
#pragma unroll
    for (int ni = 0; ni < 4; ni++){
      long gn = colBase + wn + ni * 16 + (lane & 15);
      float bb = 0.f;
      if (MODE == MODE_Q || MODE == MODE_V || MODE == MODE_OUT) bb = bias[gn];
      if (MODE == MODE_V){
        // f32 updated_v + fused bf16 transpose (vT[b,h,hd,kv])
        long gmBase = rowBase + wm + mi * 16 + ((lane >> 4) << 2);
        long b = gmBase >> 12, kv = gmBase & 4095;
        long h = gn >> 6, hd = gn & 63;
        long fidx = ((b * SH + h) * SKV + kv) * SHD + hd;
        ushort4 pk;
        float v0 = acc[mi][ni][0] + bb; outF[fidx          ] = v0; pk.x = f2bf(v0);
        float v1 = acc[mi][ni][1] + bb; outF[fidx +     SHD] = v1; pk.y = f2bf(v1);
        float v2 = acc[mi][ni][2] + bb; outF[fidx + 2 * SHD] = v2; pk.z = f2bf(v2);
        float v3 = acc[mi][ni][3] + bb; outF[fidx + 3 * SHD] = v3; pk.w = f2bf(v3);
        *reinterpret_cast<ushort4*>(outB + ((b * SH + h) * SHD + hd) * SKV + kv) = pk;
      } else {
#pragma unroll
        for (int r = 0; r < 4; r++){
          long gm = rowBase + wm + mi * 16 + ((lane >> 4) << 2) + r;
          float val = acc[mi][ni][r] + bb;
          if (MODE == MODE_OUT){
            outF[gm * 1024 + gn] = val;
          } else if (MODE == MODE_Q){
            long b = gm >> 9, s = gm & 511;
            long h = gn >> 6, hd = gn & 63;
            // fold 1/sqrt(HD)*log2e into Q: softmax runs in exp2 domain
            outB[((b * SH + h) * SS + s) * SHD + hd] = f2bf(val * QSCALE);
          } else { // MODE_K
            long b = gm >> 12, kv = gm & 4095;
            long h = gn >> 6, hd = gn & 63;
            long idx = ((b * SH + h) * SKV + kv) * SHD + hd;
            outF[idx] = val;
            outB[idx] = f2bf(val);
          }
        }
      }
    }
  }
}

// ---------- flash attention partial, swapped-operand + LDS-staged K/V ----------
// Per wave: 16 q rows. Lane c=lane&15 owns q-row c; hi=lane>>4.
// S^T[kv][q]: sT[ni][r] = S[kv=16ni+4hi+r][q=c]  (base-2 log domain, QSCALE)
// O^T[hd][q]: acc[ni][r] = O[hd=16ni+4hi+r][q=c]
__global__ __launch_bounds__(256) void attn_partial(const u16* __restrict__ qb,
                                                    const u16* __restrict__ kb,
                                                    const u16* __restrict__ vTb,
                                                    float* __restrict__ opart,
                                                    float* __restrict__ ml){
  __shared__ u16 Klds[64 * 64];             // [kv][hd], 128B rows, swizzled
  __shared__ u16 Vlds[64 * 64];             // [hd][kv], 128B rows, swizzled
  __shared__ u16 PT[4][16 * 72];            // per-wave P^T[q][kv], stride 72 u16
  const int tid  = threadIdx.x;
  const int lane = tid & 63;
  const int wid  = tid >> 6;
  const int c    = lane & 15;
  const int hi   = lane >> 4;
  const long bh  = blockIdx.x;
  const int  qt  = blockIdx.y;
  const int  split = blockIdx.z;

  const u16* qp = qb + (bh * SS + qt * 64 + wid * 16 + c) * SHD + hi * 8;
  const bf16x8 bq0 = ld_frag_g(qp);
  const bf16x8 bq1 = ld_frag_g(qp + 32);

  f32x4 acc[4];
#pragma unroll
  for (int i = 0; i < 4; i++) acc[i] = (f32x4){0.f, 0.f, 0.f, 0.f};
  float mrun = -INFINITY, lrun = 0.f;

  const u16* kbase = kb  + bh * SKV * SHD;
  const u16* vbase = vTb + bh * SHD * SKV;
  u16* pt = &PT[wid][0];
  char* kch = reinterpret_cast<char*>(Klds);
  char* vch = reinterpret_cast<char*>(Vlds);

  for (int kt = split * 16; kt < split * 16 + 16; ++kt){
    __syncthreads();                        // previous tile's readers done
#pragma unroll
    for (int i = 0; i < 2; i++){
      int u = tid + i * 256;                // [0,512): 64 rows x 8 x 16B
      int r = u >> 3, cc = u & 7;
      uint4 kv4 = *reinterpret_cast<const uint4*>(kbase + (kt * 64 + r) * SHD + cc * 8);
      uint4 vv4 = *reinterpret_cast<const uint4*>(vbase + (long)r * SKV + kt * 64 + cc * 8);
      int ob = (r * 128 + cc * 16) ^ ((r & 7) << 4);
      *reinterpret_cast<uint4*>(kch + ob) = kv4;
      *reinterpret_cast<uint4*>(vch + ob) = vv4;
    }
    __syncthreads();

    // S^T = K · Q^T : 8 MFMAs, K-frags from LDS
    f32x4 sT[4];
#pragma unroll
    for (int ni = 0; ni < 4; ni++){
      int krow = ni * 16 + c;
      int swz = (krow & 7) << 4;
      int a0 = (krow * 128 + hi * 16) ^ swz;
      int a1 = (krow * 128 + 64 + hi * 16) ^ swz;
      f32x4 z = (f32x4){0.f, 0.f, 0.f, 0.f};
      sT[ni] = __builtin_amdgcn_mfma_f32_16x16x32_bf16(ld_frag_lds(kch, a0), bq0, z, 0, 0, 0);
      sT[ni] = __builtin_amdgcn_mfma_f32_16x16x32_bf16(ld_frag_lds(kch, a1), bq1, sT[ni], 0, 0, 0);
    }
    // per-lane softmax for q-row c (base-2 domain; scale folded into Q)
    f32x4 mv = __builtin_elementwise_max(__builtin_elementwise_max(sT[0], sT[1]),
                                         __builtin_elementwise_max(sT[2], sT[3]));
    float t = fmaxf(fmaxf(mv[0], mv[1]), fmaxf(mv[2], mv[3]));
    t = fmaxf(t, __shfl_xor(t, 16));
    t = fmaxf(t, __shfl_xor(t, 32));
    float mn = fmaxf(mrun, t);
    float al = exp2f(mrun - mn);
    f32x4 psv = (f32x4){0.f, 0.f, 0.f, 0.f};
#pragma unroll
    for (int ni = 0; ni < 4; ni++){
      f32x4 p;
      p[0] = exp2f(sT[ni][0] - mn); p[1] = exp2f(sT[ni][1] - mn);
      p[2] = exp2f(sT[ni][2] - mn); p[3] = exp2f(sT[ni][3] - mn);
      psv += p;
      ushort4 pk;
      pk.x = f2bf(p[0]); pk.y = f2bf(p[1]); pk.z = f2bf(p[2]); pk.w = f2bf(p[3]);
      *reinterpret_cast<ushort4*>(pt + c * 72 + ni * 16 + hi * 4) = pk;
    }
    float ps = (psv[0] + psv[1]) + (psv[2] + psv[3]);
    ps += __shfl_xor(ps, 16);
    ps += __shfl_xor(ps, 32);
    lrun = lrun * al + ps;
    mrun = mn;
#pragma unroll
    for (int ni = 0; ni < 4; ni++) acc[ni] *= al;
    // O^T += V^T · P^T : 8 MFMAs, V-frags from LDS
#pragma unroll
    for (int m = 0; m < 2; m++){
      bf16x8 pfrag = __builtin_bit_cast(bf16x8,
          *reinterpret_cast<const uint4*>(pt + c * 72 + m * 32 + hi * 8));
#pragma unroll
      for (int ni = 0; ni < 4; ni++){
        int vrow = ni * 16 + c;
        int av = (vrow * 128 + m * 64 + hi * 16) ^ ((vrow & 7) << 4);
        acc[ni] = __builtin_amdgcn_mfma_f32_16x16x32_bf16(ld_frag_lds(vch, av), pfrag, acc[ni], 0, 0, 0);
      }
    }
  }

  // epilogue: unnormalized O^T partials + per-row m,l (m in base-2 domain)
  const long row = bh * SS + (long)qt * 64 + wid * 16 + c;
  float* ob = opart + ((long)split * NROWS + row) * SHD;
#pragma unroll
  for (int ni = 0; ni < 4; ni++)
    *reinterpret_cast<f32x4*>(ob + ni * 16 + hi * 4) = acc[ni];
  if (hi == 0){
    ml[(long)split * NROWS + row] = mrun;
    ml[(long)NSPLIT * NROWS + (long)split * NROWS + row] = lrun;
  }
}

// ---------- combine partials -> attnb bf16 [B,S,D] (base-2 weights) ----------
__global__ __launch_bounds__(256) void attn_combine(const float* __restrict__ opart,
                                                    const float* __restrict__ ml,
                                                    u16* __restrict__ attnb){
  long idx4 = (long)blockIdx.x * 256 + threadIdx.x;   // float4 id, 16 per row
  long row = idx4 >> 4;
  int  c   = (int)(idx4 & 15);
  float m0 = ml[row], m1 = ml[NROWS + row], m2 = ml[2L*NROWS + row], m3 = ml[3L*NROWS + row];
  float M = fmaxf(fmaxf(m0, m1), fmaxf(m2, m3));
  float w0 = exp2f(m0 - M), w1 = exp2f(m1 - M), w2 = exp2f(m2 - M), w3 = exp2f(m3 - M);
  const float* lb = ml + (long)NSPLIT * NROWS;
  float L = w0*lb[row] + w1*lb[NROWS+row] + w2*lb[2L*NROWS+row] + w3*lb[3L*NROWS+row];
  float inv = 1.f / L;
  const float4* op = reinterpret_cast<const float4*>(opart);
  float4 v0 = op[(0L*NROWS + row) * 16 + c];
  float4 v1 = op[(1L*NROWS + row) * 16 + c];
  float4 v2 = op[(2L*NROWS + row) * 16 + c];
  float4 v3 = op[(3L*NROWS + row) * 16 + c];
  float4 val;
  val.x = (w0*v0.x + w1*v1.x + w2*v2.x + w3*v3.x) * inv;
  val.y = (w0*v0.y + w1*v1.y + w2*v2.y + w3*v3.y) * inv;
  val.z = (w0*v0.z + w1*v1.z + w2*v2.z + w3*v3.z) * inv;
  val.w = (w0*v0.w + w1*v1.w + w2*v2.w + w3*v3.w) * inv;
  long bh = row >> 9, s = row & 511;
  long b = bh >> 4, h = bh & 15;
  ushort4 u;
  u.x = f2bf(val.x); u.y = f2bf(val.y); u.z = f2bf(val.z); u.w = f2bf(val.w);
  reinterpret_cast<ushort4*>(attnb)[((b * SS + s) * SD + h * SHD) / 4 + c] = u;
}

extern "C" void kernel_launch(void* const* d_in, const int* in_sizes, int n_in,
                              void* d_out, int out_size, void* d_ws, size_t ws_size,
                              hipStream_t stream)
{
  const float* x  = (const float*)d_in[0];
  const float* xa = (const float*)d_in[1];
  const float* Wq = (const float*)d_in[2];
  const float* bq = (const float*)d_in[3];
  const float* Wk = (const float*)d_in[4];
  const float* Wv = (const float*)d_in[5];
  const float* bv = (const float*)d_in[6];
  const float* Wo = (const float*)d_in[7];
  const float* bo = (const float*)d_in[8];

  float* outO = (float*)d_out;
  float* outK = outO + (long)SB * SS * SD;
  float* outV = outK + (long)SB * SH * SKV * SHD;

  u16* ws   = (u16*)d_ws;
  u16* xb   = ws;                                     // 2M u16 (reused as attnb)
  u16* xab  = xb   + 2097152L;                        // 16.7M u16 (reused as opart f32)
  u16* Wqb  = xab  + 16777216L;
  u16* Wkb  = Wqb  + 1048576L;
  u16* Wvb  = Wkb  + 1048576L;
  u16* Wob  = Wvb  + 1048576L;
  u16* qbuf = Wob  + 1048576L;                        // [B,H,S,HD] bf16
  u16* kbuf = qbuf + 2097152L;                        // [B,H,KV,HD] bf16
  u16* vTbuf= kbuf + 16777216L;                       // [B,H,HD,KV] bf16
  u16* mlb  = vTbuf+ 16777216L;                       // 8*32768 f32

  u16*   attnb = xb;                                  // alias: xb dead after gemm_Q
  float* opart = (float*)xab;                         // alias: xab dead after gemm_V
  float* ml    = (float*)mlb;

  auto cast_launch = [&](const float* s, u16* d, long n){
    int n4 = (int)(n / 4);
    cast_kernel<<<(n4 + 255) / 256, 256, 0, stream>>>(s, d, n4);
  };
  cast_launch(x,  xb,  2097152L);
  cast_launch(xa, xab, 16777216L);
  cast_launch(Wq, Wqb, 1048576L);
  cast_launch(Wk, Wkb, 1048576L);
  cast_launch(Wv, Wvb, 1048576L);
  cast_launch(Wo, Wob, 1048576L);

  gemm_bt<MODE_Q>  <<<dim3(16, 8),  256, 0, stream>>>(xb,  Wqb, bq, nullptr, qbuf);
  gemm_bt<MODE_K>  <<<dim3(128, 8), 256, 0, stream>>>(xab, Wkb, nullptr, outK, kbuf);
  gemm_bt<MODE_V>  <<<dim3(128, 8), 256, 0, stream>>>(xab, Wvb, bv, outV, vTbuf);
  attn_partial     <<<dim3(64, 8, NSPLIT), 256, 0, stream>>>(qbuf, kbuf, vTbuf, opart, ml);
  attn_combine     <<<2048, 256, 0, stream>>>(opart, ml, attnb);
  gemm_bt<MODE_OUT><<<dim3(16, 8),  256, 0, stream>>>(attnb, Wob, bo, outO, nullptr);
}

// Round 7
// 301.438 us; speedup vs baseline: 1.0964x; 1.0964x over previous
//
#include <hip/hip_runtime.h>
#include <hip/hip_bf16.h>

using u16 = unsigned short;
typedef __bf16 bf16x8 __attribute__((ext_vector_type(8)));
typedef float f32x4 __attribute__((ext_vector_type(4)));

// B=4, S=512, KV=4096, D=1024, H=16, HD=64
#define SB 4
#define SS 512
#define SKV 4096
#define SD 1024
#define SH 16
#define SHD 64
#define NSPLIT 4
#define NROWS 32768   // B*H*S
#define QSCALE 0.18033688011112042f   // 0.125 * log2(e): softmax in base-2 domain

__device__ inline u16 f2bf(float f){
  __hip_bfloat16 h = __float2bfloat16(f);
  return __builtin_bit_cast(u16, h);
}

__device__ inline bf16x8 ld_frag_g(const u16* p){
  uint4 v = *reinterpret_cast<const uint4*>(p);
  return __builtin_bit_cast(bf16x8, v);
}

__device__ inline bf16x8 ld_frag_lds(const char* base, int ob){
  uint4 v = *reinterpret_cast<const uint4*>(base + ob);
  return __builtin_bit_cast(bf16x8, v);
}

// ---------- f32 -> bf16 cast ----------
__global__ __launch_bounds__(256) void cast_kernel(const float* __restrict__ src,
                                                   u16* __restrict__ dst, int n4){
  int i = blockIdx.x * 256 + threadIdx.x;
  if (i < n4){
    float4 f = reinterpret_cast<const float4*>(src)[i];
    ushort4 u;
    u.x = f2bf(f.x); u.y = f2bf(f.y); u.z = f2bf(f.z); u.w = f2bf(f.w);
    reinterpret_cast<ushort4*>(dst)[i] = u;
  }
}

// ---------- GEMM (R4-verified structure): C = A * W^T (+bias) ----------
enum { MODE_Q = 0, MODE_OUT = 3 };

template<int MODE>
__global__ __launch_bounds__(256) void gemm_bt(const u16* __restrict__ A,
                                               const u16* __restrict__ W,
                                               const float* __restrict__ bias,
                                               float* __restrict__ outF,
                                               u16* __restrict__ outB)
{
  __shared__ u16 As[128*64];
  __shared__ u16 Bs[128*64];
  const int tid  = threadIdx.x;
  const int lane = tid & 63;
  const int wm   = ((tid >> 6) >> 1) * 64;
  const int wn   = ((tid >> 6) & 1) * 64;
  const long rowBase = (long)blockIdx.x * 128;
  const long colBase = (long)blockIdx.y * 128;

  f32x4 acc[4][4];
#pragma unroll
  for (int i = 0; i < 4; i++)
#pragma unroll
    for (int j = 0; j < 4; j++)
      acc[i][j] = (f32x4){0.f, 0.f, 0.f, 0.f};

  for (int kt = 0; kt < 16; ++kt){
    __syncthreads();
#pragma unroll
    for (int i = 0; i < 4; i++){
      int u = tid + i * 256;
      int r = u >> 3, c = u & 7;
      uint4 va = *reinterpret_cast<const uint4*>(A + (rowBase + r) * 1024 + kt * 64 + c * 8);
      uint4 vw = *reinterpret_cast<const uint4*>(W + (colBase + r) * 1024 + kt * 64 + c * 8);
      int ob = (r * 128 + c * 16) ^ ((r & 7) << 4);
      *reinterpret_cast<uint4*>(reinterpret_cast<char*>(As) + ob) = va;
      *reinterpret_cast<uint4*>(reinterpret_cast<char*>(Bs) + ob) = vw;
    }
    __syncthreads();
#pragma unroll
    for (int kk = 0; kk < 2; kk++){
      bf16x8 af[4], bfr[4];
#pragma unroll
      for (int mi = 0; mi < 4; mi++){
        int row = wm + mi * 16 + (lane & 15);
        int ob = (row * 128 + kk * 64 + (lane >> 4) * 16) ^ ((row & 7) << 4);
        af[mi] = ld_frag_lds(reinterpret_cast<const char*>(As), ob);
      }
#pragma unroll
      for (int ni = 0; ni < 4; ni++){
        int row = wn + ni * 16 + (lane & 15);
        int ob = (row * 128 + kk * 64 + (lane >> 4) * 16) ^ ((row & 7) << 4);
        bfr[ni] = ld_frag_lds(reinterpret_cast<const char*>(Bs), ob);
      }
#pragma unroll
      for (int mi = 0; mi < 4; mi++)
#pragma unroll
        for (int ni = 0; ni < 4; ni++)
          acc[mi][ni] = __builtin_amdgcn_mfma_f32_16x16x32_bf16(af[mi], bfr[ni], acc[mi][ni], 0, 0, 0);
    }
  }

#pragma unroll
  for (int mi = 0; mi < 4; mi++){
#pragma unroll
    for (int ni = 0; ni < 4; ni++){
      long gn = colBase + wn + ni * 16 + (lane & 15);
      float bb = bias[gn];
#pragma unroll
      for (int r = 0; r < 4; r++){
        long gm = rowBase + wm + mi * 16 + ((lane >> 4) << 2) + r;
        float val = acc[mi][ni][r] + bb;
        if (MODE == MODE_OUT){
          outF[gm * 1024 + gn] = val;
        } else { // MODE_Q: fold 1/sqrt(HD)*log2e
          long b = gm >> 9, s = gm & 511;
          long h = gn >> 6, hd = gn & 63;
          outB[((b * SH + h) * SS + s) * SHD + hd] = f2bf(val * QSCALE);
        }
      }
    }
  }
}

// ---------- fused K+V projection GEMM ----------
// Shares the A-tile (xa rows) between the K and V products: 64 MFMA per
// barrier pair (vs 32 in the split kernels), 12 staging writes (vs 16),
// af[] read once for both. Staging/epilogues byte-identical to R4's.
__global__ __launch_bounds__(256) void gemm_kv(const u16* __restrict__ A,
                                               const u16* __restrict__ Wk,
                                               const u16* __restrict__ Wv,
                                               const float* __restrict__ bv,
                                               float* __restrict__ outK,
                                               u16* __restrict__ outKb,
                                               float* __restrict__ outV,
                                               u16* __restrict__ outVTb)
{
  __shared__ u16 As [128*64];
  __shared__ u16 Bks[128*64];
  __shared__ u16 Bvs[128*64];
  const int tid  = threadIdx.x;
  const int lane = tid & 63;
  const int wm   = ((tid >> 6) >> 1) * 64;
  const int wn   = ((tid >> 6) & 1) * 64;
  const long rowBase = (long)blockIdx.x * 128;
  const long colBase = (long)blockIdx.y * 128;

  f32x4 accK[4][4], accV[4][4];
#pragma unroll
  for (int i = 0; i < 4; i++)
#pragma unroll
    for (int j = 0; j < 4; j++){
      accK[i][j] = (f32x4){0.f, 0.f, 0.f, 0.f};
      accV[i][j] = (f32x4){0.f, 0.f, 0.f, 0.f};
    }

  for (int kt = 0; kt < 16; ++kt){
    __syncthreads();
#pragma unroll
    for (int i = 0; i < 4; i++){
      int u = tid + i * 256;
      int r = u >> 3, c = u & 7;
      uint4 va = *reinterpret_cast<const uint4*>(A  + (rowBase + r) * 1024 + kt * 64 + c * 8);
      uint4 vk = *reinterpret_cast<const uint4*>(Wk + (colBase + r) * 1024 + kt * 64 + c * 8);
      uint4 vv = *reinterpret_cast<const uint4*>(Wv + (colBase + r) * 1024 + kt * 64 + c * 8);
      int ob = (r * 128 + c * 16) ^ ((r & 7) << 4);
      *reinterpret_cast<uint4*>(reinterpret_cast<char*>(As)  + ob) = va;
      *reinterpret_cast<uint4*>(reinterpret_cast<char*>(Bks) + ob) = vk;
      *reinterpret_cast<uint4*>(reinterpret_cast<char*>(Bvs) + ob) = vv;
    }
    __syncthreads();
#pragma unroll
    for (int kk = 0; kk < 2; kk++){
      bf16x8 af[4], bk[4], bvf[4];
#pragma unroll
      for (int mi = 0; mi < 4; mi++){
        int row = wm + mi * 16 + (lane & 15);
        int ob = (row * 128 + kk * 64 + (lane >> 4) * 16) ^ ((row & 7) << 4);
        af[mi] = ld_frag_lds(reinterpret_cast<const char*>(As), ob);
      }
#pragma unroll
      for (int ni = 0; ni < 4; ni++){
        int row = wn + ni * 16 + (lane & 15);
        int ob = (row * 128 + kk * 64 + (lane >> 4) * 16) ^ ((row & 7) << 4);
        bk[ni]  = ld_frag_lds(reinterpret_cast<const char*>(Bks), ob);
        bvf[ni] = ld_frag_lds(reinterpret_cast<const char*>(Bvs), ob);
      }
#pragma unroll
      for (int mi = 0; mi < 4; mi++)
#pragma unroll
        for (int ni = 0; ni < 4; ni++){
          accK[mi][ni] = __builtin_amdgcn_mfma_f32_16x16x32_bf16(af[mi], bk[ni],  accK[mi][ni], 0, 0, 0);
          accV[mi][ni] = __builtin_amdgcn_mfma_f32_16x16x32_bf16(af[mi], bvf[ni], accV[mi][ni], 0, 0, 0);
        }
    }
  }

#pragma unroll
  for (int mi = 0; mi < 4; mi++){
#pragma unroll
    for (int ni = 0; ni < 4; ni++){
      long gn = colBase + wn + ni * 16 + (lane & 15);
      long h = gn >> 6, hd = gn & 63;
      // K epilogue (no bias): f32 updated_k + bf16 copy
#pragma unroll
      for (int r = 0; r < 4; r++){
        long gm = rowBase + wm + mi * 16 + ((lane >> 4) << 2) + r;
        long b = gm >> 12, kv = gm & 4095;
        long idx = ((b * SH + h) * SKV + kv) * SHD + hd;
        float val = accK[mi][ni][r];
        outK[idx] = val;
        outKb[idx] = f2bf(val);
      }
      // V epilogue: f32 updated_v + fused bf16 transpose
      float bb = bv[gn];
      long gmBase = rowBase + wm + mi * 16 + ((lane >> 4) << 2);
      long b = gmBase >> 12, kv = gmBase & 4095;
      long fidx = ((b * SH + h) * SKV + kv) * SHD + hd;
      ushort4 pk;
      float v0 = accV[mi][ni][0] + bb; outV[fidx          ] = v0; pk.x = f2bf(v0);
      float v1 = accV[mi][ni][1] + bb; outV[fidx +     SHD] = v1; pk.y = f2bf(v1);
      float v2 = accV[mi][ni][2] + bb; outV[fidx + 2 * SHD] = v2; pk.z = f2bf(v2);
      float v3 = accV[mi][ni][3] + bb; outV[fidx + 3 * SHD] = v3; pk.w = f2bf(v3);
      *reinterpret_cast<ushort4*>(outVTb + ((b * SH + h) * SHD + hd) * SKV + kv) = pk;
    }
  }
}

// ---------- flash attention partial, swapped-operand + LDS-staged K/V ----------
// Per wave: 16 q rows. Lane c=lane&15 owns q-row c; hi=lane>>4.
// S^T[kv][q]: sT[ni][r] = S[kv=16ni+4hi+r][q=c]  (base-2 log domain, QSCALE)
// O^T[hd][q]: acc[ni][r] = O[hd=16ni+4hi+r][q=c]
__global__ __launch_bounds__(256) void attn_partial(const u16* __restrict__ qb,
                                                    const u16* __restrict__ kb,
                                                    const u16* __restrict__ vTb,
                                                    float* __restrict__ opart,
                                                    float* __restrict__ ml){
  __shared__ u16 Klds[64 * 64];             // [kv][hd], 128B rows, swizzled
  __shared__ u16 Vlds[64 * 64];             // [hd][kv], 128B rows, swizzled
  __shared__ u16 PT[4][16 * 72];            // per-wave P^T[q][kv], stride 72 u16
  const int tid  = threadIdx.x;
  const int lane = tid & 63;
  const int wid  = tid >> 6;
  const int c    = lane & 15;
  const int hi   = lane >> 4;
  const long bh  = blockIdx.x;
  const int  qt  = blockIdx.y;
  const int  split = blockIdx.z;

  const u16* qp = qb + (bh * SS + qt * 64 + wid * 16 + c) * SHD + hi * 8;
  const bf16x8 bq0 = ld_frag_g(qp);
  const bf16x8 bq1 = ld_frag_g(qp + 32);

  f32x4 acc[4];
#pragma unroll
  for (int i = 0; i < 4; i++) acc[i] = (f32x4){0.f, 0.f, 0.f, 0.f};
  float mrun = -INFINITY, lrun = 0.f;

  const u16* kbase = kb  + bh * SKV * SHD;
  const u16* vbase = vTb + bh * SHD * SKV;
  u16* pt = &PT[wid][0];
  char* kch = reinterpret_cast<char*>(Klds);
  char* vch = reinterpret_cast<char*>(Vlds);

  for (int kt = split * 16; kt < split * 16 + 16; ++kt){
    __syncthreads();                        // previous tile's readers done
#pragma unroll
    for (int i = 0; i < 2; i++){
      int u = tid + i * 256;                // [0,512): 64 rows x 8 x 16B
      int r = u >> 3, cc = u & 7;
      uint4 kv4 = *reinterpret_cast<const uint4*>(kbase + (kt * 64 + r) * SHD + cc * 8);
      uint4 vv4 = *reinterpret_cast<const uint4*>(vbase + (long)r * SKV + kt * 64 + cc * 8);
      int ob = (r * 128 + cc * 16) ^ ((r & 7) << 4);
      *reinterpret_cast<uint4*>(kch + ob) = kv4;
      *reinterpret_cast<uint4*>(vch + ob) = vv4;
    }
    __syncthreads();

    // S^T = K · Q^T : 8 MFMAs, K-frags from LDS
    f32x4 sT[4];
#pragma unroll
    for (int ni = 0; ni < 4; ni++){
      int krow = ni * 16 + c;
      int swz = (krow & 7) << 4;
      int a0 = (krow * 128 + hi * 16) ^ swz;
      int a1 = (krow * 128 + 64 + hi * 16) ^ swz;
      f32x4 z = (f32x4){0.f, 0.f, 0.f, 0.f};
      sT[ni] = __builtin_amdgcn_mfma_f32_16x16x32_bf16(ld_frag_lds(kch, a0), bq0, z, 0, 0, 0);
      sT[ni] = __builtin_amdgcn_mfma_f32_16x16x32_bf16(ld_frag_lds(kch, a1), bq1, sT[ni], 0, 0, 0);
    }
    // per-lane softmax for q-row c (base-2 domain; scale folded into Q)
    f32x4 mv = __builtin_elementwise_max(__builtin_elementwise_max(sT[0], sT[1]),
                                         __builtin_elementwise_max(sT[2], sT[3]));
    float t = fmaxf(fmaxf(mv[0], mv[1]), fmaxf(mv[2], mv[3]));
    t = fmaxf(t, __shfl_xor(t, 16));
    t = fmaxf(t, __shfl_xor(t, 32));
    float mn = fmaxf(mrun, t);
    float al = exp2f(mrun - mn);
    f32x4 psv = (f32x4){0.f, 0.f, 0.f, 0.f};
#pragma unroll
    for (int ni = 0; ni < 4; ni++){
      f32x4 p;
      p[0] = exp2f(sT[ni][0] - mn); p[1] = exp2f(sT[ni][1] - mn);
      p[2] = exp2f(sT[ni][2] - mn); p[3] = exp2f(sT[ni][3] - mn);
      psv += p;
      ushort4 pk;
      pk.x = f2bf(p[0]); pk.y = f2bf(p[1]); pk.z = f2bf(p[2]); pk.w = f2bf(p[3]);
      *reinterpret_cast<ushort4*>(pt + c * 72 + ni * 16 + hi * 4) = pk;
    }
    float ps = (psv[0] + psv[1]) + (psv[2] + psv[3]);
    ps += __shfl_xor(ps, 16);
    ps += __shfl_xor(ps, 32);
    lrun = lrun * al + ps;
    mrun = mn;
#pragma unroll
    for (int ni = 0; ni < 4; ni++) acc[ni] *= al;
    // O^T += V^T · P^T : 8 MFMAs, V-frags from LDS
#pragma unroll
    for (int m = 0; m < 2; m++){
      bf16x8 pfrag = __builtin_bit_cast(bf16x8,
          *reinterpret_cast<const uint4*>(pt + c * 72 + m * 32 + hi * 8));
#pragma unroll
      for (int ni = 0; ni < 4; ni++){
        int vrow = ni * 16 + c;
        int av = (vrow * 128 + m * 64 + hi * 16) ^ ((vrow & 7) << 4);
        acc[ni] = __builtin_amdgcn_mfma_f32_16x16x32_bf16(ld_frag_lds(vch, av), pfrag, acc[ni], 0, 0, 0);
      }
    }
  }

  // epilogue: unnormalized O^T partials + per-row m,l (m in base-2 domain)
  const long row = bh * SS + (long)qt * 64 + wid * 16 + c;
  float* ob = opart + ((long)split * NROWS + row) * SHD;
#pragma unroll
  for (int ni = 0; ni < 4; ni++)
    *reinterpret_cast<f32x4*>(ob + ni * 16 + hi * 4) = acc[ni];
  if (hi == 0){
    ml[(long)split * NROWS + row] = mrun;
    ml[(long)NSPLIT * NROWS + (long)split * NROWS + row] = lrun;
  }
}

// ---------- combine partials -> attnb bf16 [B,S,D] (base-2 weights) ----------
__global__ __launch_bounds__(256) void attn_combine(const float* __restrict__ opart,
                                                    const float* __restrict__ ml,
                                                    u16* __restrict__ attnb){
  long idx4 = (long)blockIdx.x * 256 + threadIdx.x;   // float4 id, 16 per row
  long row = idx4 >> 4;
  int  c   = (int)(idx4 & 15);
  float m0 = ml[row], m1 = ml[NROWS + row], m2 = ml[2L*NROWS + row], m3 = ml[3L*NROWS + row];
  float M = fmaxf(fmaxf(m0, m1), fmaxf(m2, m3));
  float w0 = exp2f(m0 - M), w1 = exp2f(m1 - M), w2 = exp2f(m2 - M), w3 = exp2f(m3 - M);
  const float* lb = ml + (long)NSPLIT * NROWS;
  float L = w0*lb[row] + w1*lb[NROWS+row] + w2*lb[2L*NROWS+row] + w3*lb[3L*NROWS+row];
  float inv = 1.f / L;
  const float4* op = reinterpret_cast<const float4*>(opart);
  float4 v0 = op[(0L*NROWS + row) * 16 + c];
  float4 v1 = op[(1L*NROWS + row) * 16 + c];
  float4 v2 = op[(2L*NROWS + row) * 16 + c];
  float4 v3 = op[(3L*NROWS + row) * 16 + c];
  float4 val;
  val.x = (w0*v0.x + w1*v1.x + w2*v2.x + w3*v3.x) * inv;
  val.y = (w0*v0.y + w1*v1.y + w2*v2.y + w3*v3.y) * inv;
  val.z = (w0*v0.z + w1*v1.z + w2*v2.z + w3*v3.z) * inv;
  val.w = (w0*v0.w + w1*v1.w + w2*v2.w + w3*v3.w) * inv;
  long bh = row >> 9, s = row & 511;
  long b = bh >> 4, h = bh & 15;
  ushort4 u;
  u.x = f2bf(val.x); u.y = f2bf(val.y); u.z = f2bf(val.z); u.w = f2bf(val.w);
  reinterpret_cast<ushort4*>(attnb)[((b * SS + s) * SD + h * SHD) / 4 + c] = u;
}

extern "C" void kernel_launch(void* const* d_in, const int* in_sizes, int n_in,
                              void* d_out, int out_size, void* d_ws, size_t ws_size,
                              hipStream_t stream)
{
  const float* x  = (const float*)d_in[0];
  const float* xa = (const float*)d_in[1];
  const float* Wq = (const float*)d_in[2];
  const float* bq = (const float*)d_in[3];
  const float* Wk = (const float*)d_in[4];
  const float* Wv = (const float*)d_in[5];
  const float* bv = (const float*)d_in[6];
  const float* Wo = (const float*)d_in[7];
  const float* bo = (const float*)d_in[8];

  float* outO = (float*)d_out;
  float* outK = outO + (long)SB * SS * SD;
  float* outV = outK + (long)SB * SH * SKV * SHD;

  u16* ws   = (u16*)d_ws;
  u16* xb   = ws;                                     // 2M u16 (reused as attnb)
  u16* xab  = xb   + 2097152L;                        // 16.7M u16 (reused as opart f32)
  u16* Wqb  = xab  + 16777216L;
  u16* Wkb  = Wqb  + 1048576L;
  u16* Wvb  = Wkb  + 1048576L;
  u16* Wob  = Wvb  + 1048576L;
  u16* qbuf = Wob  + 1048576L;                        // [B,H,S,HD] bf16
  u16* kbuf = qbuf + 2097152L;                        // [B,H,KV,HD] bf16
  u16* vTbuf= kbuf + 16777216L;                       // [B,H,HD,KV] bf16
  u16* mlb  = vTbuf+ 16777216L;                       // 8*32768 f32

  u16*   attnb = xb;                                  // alias: xb dead after gemm_Q
  float* opart = (float*)xab;                         // alias: xab dead after gemm_kv
  float* ml    = (float*)mlb;

  auto cast_launch = [&](const float* s, u16* d, long n){
    int n4 = (int)(n / 4);
    cast_kernel<<<(n4 + 255) / 256, 256, 0, stream>>>(s, d, n4);
  };
  cast_launch(x,  xb,  2097152L);
  cast_launch(xa, xab, 16777216L);
  cast_launch(Wq, Wqb, 1048576L);
  cast_launch(Wk, Wkb, 1048576L);
  cast_launch(Wv, Wvb, 1048576L);
  cast_launch(Wo, Wob, 1048576L);

  gemm_bt<MODE_Q>  <<<dim3(16, 8),  256, 0, stream>>>(xb,  Wqb, bq, nullptr, qbuf);
  gemm_kv          <<<dim3(128, 8), 256, 0, stream>>>(xab, Wkb, Wvb, bv,
                                                      outK, kbuf, outV, vTbuf);
  attn_partial     <<<dim3(64, 8, NSPLIT), 256, 0, stream>>>(qbuf, kbuf, vTbuf, opart, ml);
  attn_combine     <<<2048, 256, 0, stream>>>(opart, ml, attnb);
  gemm_bt<MODE_OUT><<<dim3(16, 8),  256, 0, stream>>>(attnb, Wob, bo, outO, nullptr);
}

// Round 8
// 283.940 us; speedup vs baseline: 1.1640x; 1.0616x over previous
//
#include <hip/hip_runtime.h>
#include <hip/hip_bf16.h>

using u16 = unsigned short;
typedef __bf16 bf16x8 __attribute__((ext_vector_type(8)));
typedef float f32x4 __attribute__((ext_vector_type(4)));

// B=4, S=512, KV=4096, D=1024, H=16, HD=64
#define SB 4
#define SS 512
#define SKV 4096
#define SD 1024
#define SH 16
#define SHD 64
#define NSPLIT 4
#define NROWS 32768   // B*H*S
#define QSCALE 0.18033688011112042f   // 0.125 * log2(e): softmax in base-2 domain

__device__ inline u16 f2bf(float f){
  __hip_bfloat16 h = __float2bfloat16(f);
  return __builtin_bit_cast(u16, h);
}

__device__ inline bf16x8 ld_frag_g(const u16* p){
  uint4 v = *reinterpret_cast<const uint4*>(p);
  return __builtin_bit_cast(bf16x8, v);
}

__device__ inline bf16x8 ld_frag_lds(const char* base, int ob){
  uint4 v = *reinterpret_cast<const uint4*>(base + ob);
  return __builtin_bit_cast(bf16x8, v);
}

// ---------- f32 -> bf16 cast ----------
__global__ __launch_bounds__(256) void cast_kernel(const float* __restrict__ src,
                                                   u16* __restrict__ dst, int n4){
  int i = blockIdx.x * 256 + threadIdx.x;
  if (i < n4){
    float4 f = reinterpret_cast<const float4*>(src)[i];
    ushort4 u;
    u.x = f2bf(f.x); u.y = f2bf(f.y); u.z = f2bf(f.z); u.w = f2bf(f.w);
    reinterpret_cast<ushort4*>(dst)[i] = u;
  }
}

// ---------- GEMM (R4-verified structure): C[M,N] = A[M,K]*W[N,K]^T (+bias) ----------
enum { MODE_Q = 0, MODE_K = 1, MODE_V = 2, MODE_OUT = 3 };

template<int MODE>
__global__ __launch_bounds__(256) void gemm_bt(const u16* __restrict__ A,
                                               const u16* __restrict__ W,
                                               const float* __restrict__ bias,
                                               float* __restrict__ outF,
                                               u16* __restrict__ outB)
{
  __shared__ u16 As[128*64];
  __shared__ u16 Bs[128*64];
  const int tid  = threadIdx.x;
  const int lane = tid & 63;
  const int wm   = ((tid >> 6) >> 1) * 64;
  const int wn   = ((tid >> 6) & 1) * 64;
  const long rowBase = (long)blockIdx.x * 128;
  const long colBase = (long)blockIdx.y * 128;

  f32x4 acc[4][4];
#pragma unroll
  for (int i = 0; i < 4; i++)
#pragma unroll
    for (int j = 0; j < 4; j++)
      acc[i][j] = (f32x4){0.f, 0.f, 0.f, 0.f};

  for (int kt = 0; kt < 16; ++kt){
    __syncthreads();
#pragma unroll
    for (int i = 0; i < 4; i++){
      int u = tid + i * 256;
      int r = u >> 3, c = u & 7;
      uint4 va = *reinterpret_cast<const uint4*>(A + (rowBase + r) * 1024 + kt * 64 + c * 8);
      uint4 vw = *reinterpret_cast<const uint4*>(W + (colBase + r) * 1024 + kt * 64 + c * 8);
      int ob = (r * 128 + c * 16) ^ ((r & 7) << 4);
      *reinterpret_cast<uint4*>(reinterpret_cast<char*>(As) + ob) = va;
      *reinterpret_cast<uint4*>(reinterpret_cast<char*>(Bs) + ob) = vw;
    }
    __syncthreads();
#pragma unroll
    for (int kk = 0; kk < 2; kk++){
      bf16x8 af[4], bfr[4];
#pragma unroll
      for (int mi = 0; mi < 4; mi++){
        int row = wm + mi * 16 + (lane & 15);
        int ob = (row * 128 + kk * 64 + (lane >> 4) * 16) ^ ((row & 7) << 4);
        af[mi] = ld_frag_lds(reinterpret_cast<const char*>(As), ob);
      }
#pragma unroll
      for (int ni = 0; ni < 4; ni++){
        int row = wn + ni * 16 + (lane & 15);
        int ob = (row * 128 + kk * 64 + (lane >> 4) * 16) ^ ((row & 7) << 4);
        bfr[ni] = ld_frag_lds(reinterpret_cast<const char*>(Bs), ob);
      }
#pragma unroll
      for (int mi = 0; mi < 4; mi++)
#pragma unroll
        for (int ni = 0; ni < 4; ni++)
          acc[mi][ni] = __builtin_amdgcn_mfma_f32_16x16x32_bf16(af[mi], bfr[ni], acc[mi][ni], 0, 0, 0);
    }
  }

#pragma unroll
  for (int mi = 0; mi < 4; mi++){
#pragma unroll
    for (int ni = 0; ni < 4; ni++){
      long gn = colBase + wn + ni * 16 + (lane & 15);
      float bb = 0.f;
      if (MODE == MODE_Q || MODE == MODE_V || MODE == MODE_OUT) bb = bias[gn];
      if (MODE == MODE_V){
        // f32 updated_v + fused bf16 transpose (vT[b,h,hd,kv])
        long gmBase = rowBase + wm + mi * 16 + ((lane >> 4) << 2);
        long b = gmBase >> 12, kv = gmBase & 4095;
        long h = gn >> 6, hd = gn & 63;
        long fidx = ((b * SH + h) * SKV + kv) * SHD + hd;
        ushort4 pk;
        float v0 = acc[mi][ni][0] + bb; outF[fidx          ] = v0; pk.x = f2bf(v0);
        float v1 = acc[mi][ni][1] + bb; outF[fidx +     SHD] = v1; pk.y = f2bf(v1);
        float v2 = acc[mi][ni][2] + bb; outF[fidx + 2 * SHD] = v2; pk.z = f2bf(v2);
        float v3 = acc[mi][ni][3] + bb; outF[fidx + 3 * SHD] = v3; pk.w = f2bf(v3);
        *reinterpret_cast<ushort4*>(outB + ((b * SH + h) * SHD + hd) * SKV + kv) = pk;
      } else {
#pragma unroll
        for (int r = 0; r < 4; r++){
          long gm = rowBase + wm + mi * 16 + ((lane >> 4) << 2) + r;
          float val = acc[mi][ni][r] + bb;
          if (MODE == MODE_OUT){
            outF[gm * 1024 + gn] = val;
          } else if (MODE == MODE_Q){
            long b = gm >> 9, s = gm & 511;
            long h = gn >> 6, hd = gn & 63;
            // fold 1/sqrt(HD)*log2e into Q: softmax runs in exp2 domain
            outB[((b * SH + h) * SS + s) * SHD + hd] = f2bf(val * QSCALE);
          } else { // MODE_K
            long b = gm >> 12, kv = gm & 4095;
            long h = gn >> 6, hd = gn & 63;
            long idx = ((b * SH + h) * SKV + kv) * SHD + hd;
            outF[idx] = val;
            outB[idx] = f2bf(val);
          }
        }
      }
    }
  }
}

// ---------- flash attention partial: swapped-operand, QBLK=32/wave ----------
// Per wave: 32 q rows (two 16-row groups). Lane c=lane&15, hi=lane>>4.
// Group g in {0,1}: q-row = base + c + g*16.
// S^T[kv][q]: sTg[ni][r] = S[kv=16ni+4hi+r][q]  (base-2 log domain via QSCALE)
// O^T[hd][q]: accg[ni][r] = O[hd=16ni+4hi+r][q]
// K/V staged in LDS once per block (4 waves), each frag feeds 2 MFMAs.
__global__ __launch_bounds__(256) void attn_partial(const u16* __restrict__ qb,
                                                    const u16* __restrict__ kb,
                                                    const u16* __restrict__ vTb,
                                                    float* __restrict__ opart,
                                                    float* __restrict__ ml){
  __shared__ u16 Klds[64 * 64];             // [kv][hd], 128B rows, swizzled
  __shared__ u16 Vlds[64 * 64];             // [hd][kv], 128B rows, swizzled
  __shared__ u16 PT[4][32 * 72];            // per-wave P^T[q][kv], stride 72 u16
  const int tid  = threadIdx.x;
  const int lane = tid & 63;
  const int wid  = tid >> 6;
  const int c    = lane & 15;
  const int hi   = lane >> 4;
  const long bh  = blockIdx.x;
  const int  qt  = blockIdx.y;              // q-tile of 128 rows
  const int  split = blockIdx.z;

  // Q B-frags for both q-groups: lane holds Q[q][hd = hi*8..+8] (+32: k-half 1)
  const u16* qp = qb + (bh * SS + qt * 128 + wid * 32 + c) * SHD + hi * 8;
  const bf16x8 bq0 = ld_frag_g(qp);
  const bf16x8 bq1 = ld_frag_g(qp + 32);
  const bf16x8 bq2 = ld_frag_g(qp + 16 * SHD);
  const bf16x8 bq3 = ld_frag_g(qp + 16 * SHD + 32);

  f32x4 acc0[4], acc1[4];
#pragma unroll
  for (int i = 0; i < 4; i++){
    acc0[i] = (f32x4){0.f, 0.f, 0.f, 0.f};
    acc1[i] = (f32x4){0.f, 0.f, 0.f, 0.f};
  }
  float mrun0 = -INFINITY, lrun0 = 0.f;
  float mrun1 = -INFINITY, lrun1 = 0.f;

  const u16* kbase = kb  + bh * SKV * SHD;
  const u16* vbase = vTb + bh * SHD * SKV;
  u16* pt = &PT[wid][0];
  char* kch = reinterpret_cast<char*>(Klds);
  char* vch = reinterpret_cast<char*>(Vlds);

  for (int kt = split * 16; kt < split * 16 + 16; ++kt){
    __syncthreads();                        // previous tile's readers done
#pragma unroll
    for (int i = 0; i < 2; i++){
      int u = tid + i * 256;                // [0,512): 64 rows x 8 x 16B
      int r = u >> 3, cc = u & 7;
      uint4 kv4 = *reinterpret_cast<const uint4*>(kbase + (kt * 64 + r) * SHD + cc * 8);
      uint4 vv4 = *reinterpret_cast<const uint4*>(vbase + (long)r * SKV + kt * 64 + cc * 8);
      int ob = (r * 128 + cc * 16) ^ ((r & 7) << 4);
      *reinterpret_cast<uint4*>(kch + ob) = kv4;
      *reinterpret_cast<uint4*>(vch + ob) = vv4;
    }
    __syncthreads();

    // S^T = K · Q^T : 16 MFMAs (each K-frag pair feeds both q-groups)
    f32x4 sT0[4], sT1[4];
#pragma unroll
    for (int ni = 0; ni < 4; ni++){
      int krow = ni * 16 + c;
      int swz = (krow & 7) << 4;
      bf16x8 kf0 = ld_frag_lds(kch, (krow * 128 + hi * 16) ^ swz);
      bf16x8 kf1 = ld_frag_lds(kch, (krow * 128 + 64 + hi * 16) ^ swz);
      f32x4 z = (f32x4){0.f, 0.f, 0.f, 0.f};
      sT0[ni] = __builtin_amdgcn_mfma_f32_16x16x32_bf16(kf0, bq0, z, 0, 0, 0);
      sT0[ni] = __builtin_amdgcn_mfma_f32_16x16x32_bf16(kf1, bq1, sT0[ni], 0, 0, 0);
      sT1[ni] = __builtin_amdgcn_mfma_f32_16x16x32_bf16(kf0, bq2, z, 0, 0, 0);
      sT1[ni] = __builtin_amdgcn_mfma_f32_16x16x32_bf16(kf1, bq3, sT1[ni], 0, 0, 0);
    }
    // per-lane softmax, two independent q-rows (base-2 domain)
#pragma unroll
    for (int g = 0; g < 2; g++){
      f32x4* sT = g ? sT1 : sT0;
      f32x4* ac = g ? acc1 : acc0;
      float& mrun = g ? mrun1 : mrun0;
      float& lrun = g ? lrun1 : lrun0;
      f32x4 mv = __builtin_elementwise_max(__builtin_elementwise_max(sT[0], sT[1]),
                                           __builtin_elementwise_max(sT[2], sT[3]));
      float t = fmaxf(fmaxf(mv[0], mv[1]), fmaxf(mv[2], mv[3]));
      t = fmaxf(t, __shfl_xor(t, 16));
      t = fmaxf(t, __shfl_xor(t, 32));
      float mn = fmaxf(mrun, t);
      float al = exp2f(mrun - mn);
      f32x4 psv = (f32x4){0.f, 0.f, 0.f, 0.f};
#pragma unroll
      for (int ni = 0; ni < 4; ni++){
        f32x4 p;
        p[0] = exp2f(sT[ni][0] - mn); p[1] = exp2f(sT[ni][1] - mn);
        p[2] = exp2f(sT[ni][2] - mn); p[3] = exp2f(sT[ni][3] - mn);
        psv += p;
        ushort4 pk;
        pk.x = f2bf(p[0]); pk.y = f2bf(p[1]); pk.z = f2bf(p[2]); pk.w = f2bf(p[3]);
        *reinterpret_cast<ushort4*>(pt + (c + g * 16) * 72 + ni * 16 + hi * 4) = pk;
      }
      float ps = (psv[0] + psv[1]) + (psv[2] + psv[3]);
      ps += __shfl_xor(ps, 16);
      ps += __shfl_xor(ps, 32);
      lrun = lrun * al + ps;
      mrun = mn;
#pragma unroll
      for (int ni = 0; ni < 4; ni++) ac[ni] *= al;
    }
    // O^T += V^T · P^T : 16 MFMAs (each V-frag feeds both q-groups)
#pragma unroll
    for (int m = 0; m < 2; m++){
      bf16x8 pf0 = __builtin_bit_cast(bf16x8,
          *reinterpret_cast<const uint4*>(pt + c * 72 + m * 32 + hi * 8));
      bf16x8 pf1 = __builtin_bit_cast(bf16x8,
          *reinterpret_cast<const uint4*>(pt + (c + 16) * 72 + m * 32 + hi * 8));
#pragma unroll
      for (int ni = 0; ni < 4; ni++){
        int vrow = ni * 16 + c;
        bf16x8 vf = ld_frag_lds(vch, (vrow * 128 + m * 64 + hi * 16) ^ ((vrow & 7) << 4));
        acc0[ni] = __builtin_amdgcn_mfma_f32_16x16x32_bf16(vf, pf0, acc0[ni], 0, 0, 0);
        acc1[ni] = __builtin_amdgcn_mfma_f32_16x16x32_bf16(vf, pf1, acc1[ni], 0, 0, 0);
      }
    }
  }

  // epilogue: unnormalized O^T partials + per-row m,l (m in base-2 domain)
  const long row0 = bh * SS + (long)qt * 128 + wid * 32 + c;
  const long row1 = row0 + 16;
  float* ob0 = opart + ((long)split * NROWS + row0) * SHD;
  float* ob1 = opart + ((long)split * NROWS + row1) * SHD;
#pragma unroll
  for (int ni = 0; ni < 4; ni++){
    *reinterpret_cast<f32x4*>(ob0 + ni * 16 + hi * 4) = acc0[ni];
    *reinterpret_cast<f32x4*>(ob1 + ni * 16 + hi * 4) = acc1[ni];
  }
  if (hi == 0){
    ml[(long)split * NROWS + row0] = mrun0;
    ml[(long)NSPLIT * NROWS + (long)split * NROWS + row0] = lrun0;
    ml[(long)split * NROWS + row1] = mrun1;
    ml[(long)NSPLIT * NROWS + (long)split * NROWS + row1] = lrun1;
  }
}

// ---------- combine partials -> attnb bf16 [B,S,D] (base-2 weights) ----------
__global__ __launch_bounds__(256) void attn_combine(const float* __restrict__ opart,
                                                    const float* __restrict__ ml,
                                                    u16* __restrict__ attnb){
  long idx4 = (long)blockIdx.x * 256 + threadIdx.x;   // float4 id, 16 per row
  long row = idx4 >> 4;
  int  c   = (int)(idx4 & 15);
  float m0 = ml[row], m1 = ml[NROWS + row], m2 = ml[2L*NROWS + row], m3 = ml[3L*NROWS + row];
  float M = fmaxf(fmaxf(m0, m1), fmaxf(m2, m3));
  float w0 = exp2f(m0 - M), w1 = exp2f(m1 - M), w2 = exp2f(m2 - M), w3 = exp2f(m3 - M);
  const float* lb = ml + (long)NSPLIT * NROWS;
  float L = w0*lb[row] + w1*lb[NROWS+row] + w2*lb[2L*NROWS+row] + w3*lb[3L*NROWS+row];
  float inv = 1.f / L;
  const float4* op = reinterpret_cast<const float4*>(opart);
  float4 v0 = op[(0L*NROWS + row) * 16 + c];
  float4 v1 = op[(1L*NROWS + row) * 16 + c];
  float4 v2 = op[(2L*NROWS + row) * 16 + c];
  float4 v3 = op[(3L*NROWS + row) * 16 + c];
  float4 val;
  val.x = (w0*v0.x + w1*v1.x + w2*v2.x + w3*v3.x) * inv;
  val.y = (w0*v0.y + w1*v1.y + w2*v2.y + w3*v3.y) * inv;
  val.z = (w0*v0.z + w1*v1.z + w2*v2.z + w3*v3.z) * inv;
  val.w = (w0*v0.w + w1*v1.w + w2*v2.w + w3*v3.w) * inv;
  long bh = row >> 9, s = row & 511;
  long b = bh >> 4, h = bh & 15;
  ushort4 u;
  u.x = f2bf(val.x); u.y = f2bf(val.y); u.z = f2bf(val.z); u.w = f2bf(val.w);
  reinterpret_cast<ushort4*>(attnb)[((b * SS + s) * SD + h * SHD) / 4 + c] = u;
}

extern "C" void kernel_launch(void* const* d_in, const int* in_sizes, int n_in,
                              void* d_out, int out_size, void* d_ws, size_t ws_size,
                              hipStream_t stream)
{
  const float* x  = (const float*)d_in[0];
  const float* xa = (const float*)d_in[1];
  const float* Wq = (const float*)d_in[2];
  const float* bq = (const float*)d_in[3];
  const float* Wk = (const float*)d_in[4];
  const float* Wv = (const float*)d_in[5];
  const float* bv = (const float*)d_in[6];
  const float* Wo = (const float*)d_in[7];
  const float* bo = (const float*)d_in[8];

  float* outO = (float*)d_out;
  float* outK = outO + (long)SB * SS * SD;
  float* outV = outK + (long)SB * SH * SKV * SHD;

  u16* ws   = (u16*)d_ws;
  u16* xb   = ws;                                     // 2M u16 (reused as attnb)
  u16* xab  = xb   + 2097152L;                        // 16.7M u16 (reused as opart f32)
  u16* Wqb  = xab  + 16777216L;
  u16* Wkb  = Wqb  + 1048576L;
  u16* Wvb  = Wkb  + 1048576L;
  u16* Wob  = Wvb  + 1048576L;
  u16* qbuf = Wob  + 1048576L;                        // [B,H,S,HD] bf16
  u16* kbuf = qbuf + 2097152L;                        // [B,H,KV,HD] bf16
  u16* vTbuf= kbuf + 16777216L;                       // [B,H,HD,KV] bf16
  u16* mlb  = vTbuf+ 16777216L;                       // 8*32768 f32

  u16*   attnb = xb;                                  // alias: xb dead after gemm_Q
  float* opart = (float*)xab;                         // alias: xab dead after gemm_V
  float* ml    = (float*)mlb;

  auto cast_launch = [&](const float* s, u16* d, long n){
    int n4 = (int)(n / 4);
    cast_kernel<<<(n4 + 255) / 256, 256, 0, stream>>>(s, d, n4);
  };
  cast_launch(x,  xb,  2097152L);
  cast_launch(xa, xab, 16777216L);
  cast_launch(Wq, Wqb, 1048576L);
  cast_launch(Wk, Wkb, 1048576L);
  cast_launch(Wv, Wvb, 1048576L);
  cast_launch(Wo, Wob, 1048576L);

  gemm_bt<MODE_Q>  <<<dim3(16, 8),  256, 0, stream>>>(xb,  Wqb, bq, nullptr, qbuf);
  gemm_bt<MODE_K>  <<<dim3(128, 8), 256, 0, stream>>>(xab, Wkb, nullptr, outK, kbuf);
  gemm_bt<MODE_V>  <<<dim3(128, 8), 256, 0, stream>>>(xab, Wvb, bv, outV, vTbuf);
  attn_partial     <<<dim3(64, 4, NSPLIT), 256, 0, stream>>>(qbuf, kbuf, vTbuf, opart, ml);
  attn_combine     <<<2048, 256, 0, stream>>>(opart, ml, attnb);
  gemm_bt<MODE_OUT><<<dim3(16, 8),  256, 0, stream>>>(attnb, Wob, bo, outO, nullptr);
}

// Round 9
// 267.970 us; speedup vs baseline: 1.2334x; 1.0596x over previous
//
#include <hip/hip_runtime.h>
#include <hip/hip_bf16.h>

using u16 = unsigned short;
typedef __bf16 bf16x8 __attribute__((ext_vector_type(8)));
typedef float f32x4 __attribute__((ext_vector_type(4)));

// B=4, S=512, KV=4096, D=1024, H=16, HD=64
#define SB 4
#define SS 512
#define SKV 4096
#define SD 1024
#define SH 16
#define SHD 64
#define NSPLIT 4
#define NROWS 32768   // B*H*S
#define QSCALE 0.18033688011112042f   // 0.125 * log2(e): softmax in base-2 domain

__device__ inline u16 f2bf(float f){
  __hip_bfloat16 h = __float2bfloat16(f);
  return __builtin_bit_cast(u16, h);
}
__device__ inline float bf2f(u16 u){
  return __builtin_bit_cast(float, (unsigned)u << 16);
}

__device__ inline bf16x8 ld_frag_g(const u16* p){
  uint4 v = *reinterpret_cast<const uint4*>(p);
  return __builtin_bit_cast(bf16x8, v);
}

__device__ inline bf16x8 ld_frag_lds(const char* base, int ob){
  uint4 v = *reinterpret_cast<const uint4*>(base + ob);
  return __builtin_bit_cast(bf16x8, v);
}

// ---------- f32 -> bf16 cast ----------
__global__ __launch_bounds__(256) void cast_kernel(const float* __restrict__ src,
                                                   u16* __restrict__ dst, int n4){
  int i = blockIdx.x * 256 + threadIdx.x;
  if (i < n4){
    float4 f = reinterpret_cast<const float4*>(src)[i];
    ushort4 u;
    u.x = f2bf(f.x); u.y = f2bf(f.y); u.z = f2bf(f.z); u.w = f2bf(f.w);
    reinterpret_cast<ushort4*>(dst)[i] = u;
  }
}

// 4 weight matrices (1M f32 each) in one launch; dst stride 1M u16
__global__ __launch_bounds__(256) void cast_w4(const float* __restrict__ s0,
                                               const float* __restrict__ s1,
                                               const float* __restrict__ s2,
                                               const float* __restrict__ s3,
                                               u16* __restrict__ dst){
  int which = blockIdx.x >> 10;             // 1024 blocks per weight
  int j = (blockIdx.x & 1023) * 256 + threadIdx.x;   // float4 id in [0, 262144)
  const float* s = which == 0 ? s0 : which == 1 ? s1 : which == 2 ? s2 : s3;
  float4 f = reinterpret_cast<const float4*>(s)[j];
  ushort4 u;
  u.x = f2bf(f.x); u.y = f2bf(f.y); u.z = f2bf(f.z); u.w = f2bf(f.w);
  reinterpret_cast<ushort4*>(dst + (long)which * 1048576L)[j] = u;
}

// ---------- GEMM (R4-verified structure): C[M,N] = A[M,K]*W[N,K]^T (+bias) ----------
// SWZ=1: 1D grid 1024, XCD-chunked remap — each XCD gets 16 row-tiles x 8
// col-tiles processed ROW-major (the 8 blocks sharing an A-tile are
// temporally adjacent on one XCD -> A re-reads hit that XCD's L2).
enum { MODE_Q = 0, MODE_K = 1, MODE_V = 2, MODE_OUT = 3 };

template<int MODE, int SWZ>
__global__ __launch_bounds__(256) void gemm_bt(const u16* __restrict__ A,
                                               const u16* __restrict__ W,
                                               const float* __restrict__ bias,
                                               float* __restrict__ outF,
                                               u16* __restrict__ outB)
{
  __shared__ u16 As[128*64];
  __shared__ u16 Bs[128*64];
  const int tid  = threadIdx.x;
  const int lane = tid & 63;
  const int wm   = ((tid >> 6) >> 1) * 64;
  const int wn   = ((tid >> 6) & 1) * 64;
  long rowBase, colBase;
  if (SWZ){
    int lin = blockIdx.x;                   // 1024 blocks, 1024%8==0 (bijective)
    int xcd = lin & 7, j = lin >> 3;        // j in [0,128)
    int row = xcd * 16 + (j >> 3);          // 16 row-tiles per XCD
    int col = j & 7;                        // row-major col sweep
    rowBase = (long)row * 128;
    colBase = (long)col * 128;
  } else {
    rowBase = (long)blockIdx.x * 128;
    colBase = (long)blockIdx.y * 128;
  }

  f32x4 acc[4][4];
#pragma unroll
  for (int i = 0; i < 4; i++)
#pragma unroll
    for (int j = 0; j < 4; j++)
      acc[i][j] = (f32x4){0.f, 0.f, 0.f, 0.f};

  for (int kt = 0; kt < 16; ++kt){
    __syncthreads();
#pragma unroll
    for (int i = 0; i < 4; i++){
      int u = tid + i * 256;
      int r = u >> 3, c = u & 7;
      uint4 va = *reinterpret_cast<const uint4*>(A + (rowBase + r) * 1024 + kt * 64 + c * 8);
      uint4 vw = *reinterpret_cast<const uint4*>(W + (colBase + r) * 1024 + kt * 64 + c * 8);
      int ob = (r * 128 + c * 16) ^ ((r & 7) << 4);
      *reinterpret_cast<uint4*>(reinterpret_cast<char*>(As) + ob) = va;
      *reinterpret_cast<uint4*>(reinterpret_cast<char*>(Bs) + ob) = vw;
    }
    __syncthreads();
#pragma unroll
    for (int kk = 0; kk < 2; kk++){
      bf16x8 af[4], bfr[4];
#pragma unroll
      for (int mi = 0; mi < 4; mi++){
        int row = wm + mi * 16 + (lane & 15);
        int ob = (row * 128 + kk * 64 + (lane >> 4) * 16) ^ ((row & 7) << 4);
        af[mi] = ld_frag_lds(reinterpret_cast<const char*>(As), ob);
      }
#pragma unroll
      for (int ni = 0; ni < 4; ni++){
        int row = wn + ni * 16 + (lane & 15);
        int ob = (row * 128 + kk * 64 + (lane >> 4) * 16) ^ ((row & 7) << 4);
        bfr[ni] = ld_frag_lds(reinterpret_cast<const char*>(Bs), ob);
      }
#pragma unroll
      for (int mi = 0; mi < 4; mi++)
#pragma unroll
        for (int ni = 0; ni < 4; ni++)
          acc[mi][ni] = __builtin_amdgcn_mfma_f32_16x16x32_bf16(af[mi], bfr[ni], acc[mi][ni], 0, 0, 0);
    }
  }

#pragma unroll
  for (int mi = 0; mi < 4; mi++){
#pragma unroll
    for (int ni = 0; ni < 4; ni++){
      long gn = colBase + wn + ni * 16 + (lane & 15);
      float bb = 0.f;
      if (MODE == MODE_Q || MODE == MODE_V || MODE == MODE_OUT) bb = bias[gn];
      if (MODE == MODE_V){
        // f32 updated_v + fused bf16 transpose (vT[b,h,hd,kv])
        long gmBase = rowBase + wm + mi * 16 + ((lane >> 4) << 2);
        long b = gmBase >> 12, kv = gmBase & 4095;
        long h = gn >> 6, hd = gn & 63;
        long fidx = ((b * SH + h) * SKV + kv) * SHD + hd;
        ushort4 pk;
        float v0 = acc[mi][ni][0] + bb; outF[fidx          ] = v0; pk.x = f2bf(v0);
        float v1 = acc[mi][ni][1] + bb; outF[fidx +     SHD] = v1; pk.y = f2bf(v1);
        float v2 = acc[mi][ni][2] + bb; outF[fidx + 2 * SHD] = v2; pk.z = f2bf(v2);
        float v3 = acc[mi][ni][3] + bb; outF[fidx + 3 * SHD] = v3; pk.w = f2bf(v3);
        *reinterpret_cast<ushort4*>(outB + ((b * SH + h) * SHD + hd) * SKV + kv) = pk;
      } else {
#pragma unroll
        for (int r = 0; r < 4; r++){
          long gm = rowBase + wm + mi * 16 + ((lane >> 4) << 2) + r;
          float val = acc[mi][ni][r] + bb;
          if (MODE == MODE_OUT){
            outF[gm * 1024 + gn] = val;
          } else if (MODE == MODE_Q){
            long b = gm >> 9, s = gm & 511;
            long h = gn >> 6, hd = gn & 63;
            // fold 1/sqrt(HD)*log2e into Q: softmax runs in exp2 domain
            outB[((b * SH + h) * SS + s) * SHD + hd] = f2bf(val * QSCALE);
          } else { // MODE_K
            long b = gm >> 12, kv = gm & 4095;
            long h = gn >> 6, hd = gn & 63;
            long idx = ((b * SH + h) * SKV + kv) * SHD + hd;
            outF[idx] = val;
            outB[idx] = f2bf(val);
          }
        }
      }
    }
  }
}

// ---------- flash attention partial (R6-verified): QBLK=16, swapped-operand ----------
// Per wave: 16 q rows. Lane c=lane&15 owns q-row c; hi=lane>>4.
// S^T[kv][q]: sT[ni][r] = S[kv=16ni+4hi+r][q=c]  (base-2 log domain via QSCALE)
// O^T[hd][q]: acc[ni][r] = O[hd=16ni+4hi+r][q=c]
__global__ __launch_bounds__(256) void attn_partial(const u16* __restrict__ qb,
                                                    const u16* __restrict__ kb,
                                                    const u16* __restrict__ vTb,
                                                    u16* __restrict__ opartB,
                                                    float* __restrict__ ml){
  __shared__ u16 Klds[64 * 64];             // [kv][hd], 128B rows, swizzled
  __shared__ u16 Vlds[64 * 64];             // [hd][kv], 128B rows, swizzled
  __shared__ u16 PT[4][16 * 72];            // per-wave P^T[q][kv], stride 72 u16
  const int tid  = threadIdx.x;
  const int lane = tid & 63;
  const int wid  = tid >> 6;
  const int c    = lane & 15;
  const int hi   = lane >> 4;
  const long bh  = blockIdx.x;
  const int  qt  = blockIdx.y;
  const int  split = blockIdx.z;

  const u16* qp = qb + (bh * SS + qt * 64 + wid * 16 + c) * SHD + hi * 8;
  const bf16x8 bq0 = ld_frag_g(qp);
  const bf16x8 bq1 = ld_frag_g(qp + 32);

  f32x4 acc[4];
#pragma unroll
  for (int i = 0; i < 4; i++) acc[i] = (f32x4){0.f, 0.f, 0.f, 0.f};
  float mrun = -INFINITY, lrun = 0.f;

  const u16* kbase = kb  + bh * SKV * SHD;
  const u16* vbase = vTb + bh * SHD * SKV;
  u16* pt = &PT[wid][0];
  char* kch = reinterpret_cast<char*>(Klds);
  char* vch = reinterpret_cast<char*>(Vlds);

  for (int kt = split * 16; kt < split * 16 + 16; ++kt){
    __syncthreads();                        // previous tile's readers done
#pragma unroll
    for (int i = 0; i < 2; i++){
      int u = tid + i * 256;                // [0,512): 64 rows x 8 x 16B
      int r = u >> 3, cc = u & 7;
      uint4 kv4 = *reinterpret_cast<const uint4*>(kbase + (kt * 64 + r) * SHD + cc * 8);
      uint4 vv4 = *reinterpret_cast<const uint4*>(vbase + (long)r * SKV + kt * 64 + cc * 8);
      int ob = (r * 128 + cc * 16) ^ ((r & 7) << 4);
      *reinterpret_cast<uint4*>(kch + ob) = kv4;
      *reinterpret_cast<uint4*>(vch + ob) = vv4;
    }
    __syncthreads();

    // S^T = K · Q^T : 8 MFMAs, K-frags from LDS
    f32x4 sT[4];
#pragma unroll
    for (int ni = 0; ni < 4; ni++){
      int krow = ni * 16 + c;
      int swz = (krow & 7) << 4;
      int a0 = (krow * 128 + hi * 16) ^ swz;
      int a1 = (krow * 128 + 64 + hi * 16) ^ swz;
      f32x4 z = (f32x4){0.f, 0.f, 0.f, 0.f};
      sT[ni] = __builtin_amdgcn_mfma_f32_16x16x32_bf16(ld_frag_lds(kch, a0), bq0, z, 0, 0, 0);
      sT[ni] = __builtin_amdgcn_mfma_f32_16x16x32_bf16(ld_frag_lds(kch, a1), bq1, sT[ni], 0, 0, 0);
    }
    // per-lane softmax for q-row c (base-2 domain; scale folded into Q)
    f32x4 mv = __builtin_elementwise_max(__builtin_elementwise_max(sT[0], sT[1]),
                                         __builtin_elementwise_max(sT[2], sT[3]));
    float t = fmaxf(fmaxf(mv[0], mv[1]), fmaxf(mv[2], mv[3]));
    t = fmaxf(t, __shfl_xor(t, 16));
    t = fmaxf(t, __shfl_xor(t, 32));
    float mn = fmaxf(mrun, t);
    float al = exp2f(mrun - mn);
    f32x4 psv = (f32x4){0.f, 0.f, 0.f, 0.f};
#pragma unroll
    for (int ni = 0; ni < 4; ni++){
      f32x4 p;
      p[0] = exp2f(sT[ni][0] - mn); p[1] = exp2f(sT[ni][1] - mn);
      p[2] = exp2f(sT[ni][2] - mn); p[3] = exp2f(sT[ni][3] - mn);
      psv += p;
      ushort4 pk;
      pk.x = f2bf(p[0]); pk.y = f2bf(p[1]); pk.z = f2bf(p[2]); pk.w = f2bf(p[3]);
      *reinterpret_cast<ushort4*>(pt + c * 72 + ni * 16 + hi * 4) = pk;
    }
    float ps = (psv[0] + psv[1]) + (psv[2] + psv[3]);
    ps += __shfl_xor(ps, 16);
    ps += __shfl_xor(ps, 32);
    lrun = lrun * al + ps;
    mrun = mn;
#pragma unroll
    for (int ni = 0; ni < 4; ni++) acc[ni] *= al;
    // O^T += V^T · P^T : 8 MFMAs, V-frags from LDS
#pragma unroll
    for (int m = 0; m < 2; m++){
      bf16x8 pfrag = __builtin_bit_cast(bf16x8,
          *reinterpret_cast<const uint4*>(pt + c * 72 + m * 32 + hi * 8));
#pragma unroll
      for (int ni = 0; ni < 4; ni++){
        int vrow = ni * 16 + c;
        int av = (vrow * 128 + m * 64 + hi * 16) ^ ((vrow & 7) << 4);
        acc[ni] = __builtin_amdgcn_mfma_f32_16x16x32_bf16(ld_frag_lds(vch, av), pfrag, acc[ni], 0, 0, 0);
      }
    }
  }

  // epilogue: unnormalized O^T partials (bf16) + per-row m,l (m in base-2 domain)
  const long row = bh * SS + (long)qt * 64 + wid * 16 + c;
  u16* ob = opartB + ((long)split * NROWS + row) * SHD;
#pragma unroll
  for (int ni = 0; ni < 4; ni++){
    ushort4 pk;
    pk.x = f2bf(acc[ni][0]); pk.y = f2bf(acc[ni][1]);
    pk.z = f2bf(acc[ni][2]); pk.w = f2bf(acc[ni][3]);
    *reinterpret_cast<ushort4*>(ob + ni * 16 + hi * 4) = pk;
  }
  if (hi == 0){
    ml[(long)split * NROWS + row] = mrun;
    ml[(long)NSPLIT * NROWS + (long)split * NROWS + row] = lrun;
  }
}

// ---------- combine bf16 partials -> attnb bf16 [B,S,D] (base-2 weights) ----------
__global__ __launch_bounds__(256) void attn_combine(const u16* __restrict__ opartB,
                                                    const float* __restrict__ ml,
                                                    u16* __restrict__ attnb){
  long idx4 = (long)blockIdx.x * 256 + threadIdx.x;   // ushort4 id, 16 per row
  long row = idx4 >> 4;
  int  c   = (int)(idx4 & 15);
  float m0 = ml[row], m1 = ml[NROWS + row], m2 = ml[2L*NROWS + row], m3 = ml[3L*NROWS + row];
  float M = fmaxf(fmaxf(m0, m1), fmaxf(m2, m3));
  float w0 = exp2f(m0 - M), w1 = exp2f(m1 - M), w2 = exp2f(m2 - M), w3 = exp2f(m3 - M);
  const float* lb = ml + (long)NSPLIT * NROWS;
  float L = w0*lb[row] + w1*lb[NROWS+row] + w2*lb[2L*NROWS+row] + w3*lb[3L*NROWS+row];
  float inv = 1.f / L;
  const ushort4* op = reinterpret_cast<const ushort4*>(opartB);
  ushort4 v0 = op[(0L*NROWS + row) * 16 + c];
  ushort4 v1 = op[(1L*NROWS + row) * 16 + c];
  ushort4 v2 = op[(2L*NROWS + row) * 16 + c];
  ushort4 v3 = op[(3L*NROWS + row) * 16 + c];
  float4 val;
  val.x = (w0*bf2f(v0.x) + w1*bf2f(v1.x) + w2*bf2f(v2.x) + w3*bf2f(v3.x)) * inv;
  val.y = (w0*bf2f(v0.y) + w1*bf2f(v1.y) + w2*bf2f(v2.y) + w3*bf2f(v3.y)) * inv;
  val.z = (w0*bf2f(v0.z) + w1*bf2f(v1.z) + w2*bf2f(v2.z) + w3*bf2f(v3.z)) * inv;
  val.w = (w0*bf2f(v0.w) + w1*bf2f(v1.w) + w2*bf2f(v2.w) + w3*bf2f(v3.w)) * inv;
  long bh = row >> 9, s = row & 511;
  long b = bh >> 4, h = bh & 15;
  ushort4 u;
  u.x = f2bf(val.x); u.y = f2bf(val.y); u.z = f2bf(val.z); u.w = f2bf(val.w);
  reinterpret_cast<ushort4*>(attnb)[((b * SS + s) * SD + h * SHD) / 4 + c] = u;
}

extern "C" void kernel_launch(void* const* d_in, const int* in_sizes, int n_in,
                              void* d_out, int out_size, void* d_ws, size_t ws_size,
                              hipStream_t stream)
{
  const float* x  = (const float*)d_in[0];
  const float* xa = (const float*)d_in[1];
  const float* Wq = (const float*)d_in[2];
  const float* bq = (const float*)d_in[3];
  const float* Wk = (const float*)d_in[4];
  const float* Wv = (const float*)d_in[5];
  const float* bv = (const float*)d_in[6];
  const float* Wo = (const float*)d_in[7];
  const float* bo = (const float*)d_in[8];

  float* outO = (float*)d_out;
  float* outK = outO + (long)SB * SS * SD;
  float* outV = outK + (long)SB * SH * SKV * SHD;

  u16* ws   = (u16*)d_ws;
  u16* xb   = ws;                                     // 2M u16 (reused as attnb)
  u16* xab  = xb   + 2097152L;                        // 16.7M u16 (reused as opartB)
  u16* Wqb  = xab  + 16777216L;
  u16* Wkb  = Wqb  + 1048576L;
  u16* Wvb  = Wkb  + 1048576L;
  u16* Wob  = Wvb  + 1048576L;
  u16* qbuf = Wob  + 1048576L;                        // [B,H,S,HD] bf16
  u16* kbuf = qbuf + 2097152L;                        // [B,H,KV,HD] bf16
  u16* vTbuf= kbuf + 16777216L;                       // [B,H,HD,KV] bf16
  u16* mlb  = vTbuf+ 16777216L;                       // 8*32768 f32

  u16*   attnb  = xb;                                 // alias: xb dead after gemm_Q
  u16*   opartB = xab;                                // alias: xab dead after gemm_V
  float* ml     = (float*)mlb;

  cast_kernel<<<2048, 256, 0, stream>>>(x,  xb,  524288);     // 2M f32
  cast_kernel<<<16384, 256, 0, stream>>>(xa, xab, 4194304);   // 16.7M f32
  cast_w4    <<<4096, 256, 0, stream>>>(Wq, Wk, Wv, Wo, Wqb); // 4x 1M f32

  gemm_bt<MODE_Q, 0>  <<<dim3(16, 8), 256, 0, stream>>>(xb,  Wqb, bq, nullptr, qbuf);
  gemm_bt<MODE_K, 1>  <<<1024,        256, 0, stream>>>(xab, Wkb, nullptr, outK, kbuf);
  gemm_bt<MODE_V, 1>  <<<1024,        256, 0, stream>>>(xab, Wvb, bv, outV, vTbuf);
  attn_partial        <<<dim3(64, 8, NSPLIT), 256, 0, stream>>>(qbuf, kbuf, vTbuf, opartB, ml);
  attn_combine        <<<2048, 256, 0, stream>>>(opartB, ml, attnb);
  gemm_bt<MODE_OUT, 0><<<dim3(16, 8), 256, 0, stream>>>(attnb, Wob, bo, outO, nullptr);
}

// Round 10
// 262.678 us; speedup vs baseline: 1.2582x; 1.0201x over previous
//
#include <hip/hip_runtime.h>
#include <hip/hip_bf16.h>

using u16 = unsigned short;
typedef __bf16 bf16x8 __attribute__((ext_vector_type(8)));
typedef float f32x4 __attribute__((ext_vector_type(4)));

// B=4, S=512, KV=4096, D=1024, H=16, HD=64
#define SB 4
#define SS 512
#define SKV 4096
#define SD 1024
#define SH 16
#define SHD 64
#define NSPLIT 4
#define NROWS 32768   // B*H*S
#define QSCALE 0.18033688011112042f   // 0.125 * log2(e): softmax in base-2 domain

__device__ inline u16 f2bf(float f){
  __hip_bfloat16 h = __float2bfloat16(f);
  return __builtin_bit_cast(u16, h);
}
__device__ inline float bf2f(u16 u){
  return __builtin_bit_cast(float, (unsigned)u << 16);
}

__device__ inline bf16x8 ld_frag_g(const u16* p){
  uint4 v = *reinterpret_cast<const uint4*>(p);
  return __builtin_bit_cast(bf16x8, v);
}

__device__ inline bf16x8 ld_frag_lds(const char* base, int ob){
  uint4 v = *reinterpret_cast<const uint4*>(base + ob);
  return __builtin_bit_cast(bf16x8, v);
}

// ---------- f32 -> bf16 cast ----------
__global__ __launch_bounds__(256) void cast_kernel(const float* __restrict__ src,
                                                   u16* __restrict__ dst, int n4){
  int i = blockIdx.x * 256 + threadIdx.x;
  if (i < n4){
    float4 f = reinterpret_cast<const float4*>(src)[i];
    ushort4 u;
    u.x = f2bf(f.x); u.y = f2bf(f.y); u.z = f2bf(f.z); u.w = f2bf(f.w);
    reinterpret_cast<ushort4*>(dst)[i] = u;
  }
}

// 4 weight matrices (1M f32 each) in one launch; dst stride 1M u16
__global__ __launch_bounds__(256) void cast_w4(const float* __restrict__ s0,
                                               const float* __restrict__ s1,
                                               const float* __restrict__ s2,
                                               const float* __restrict__ s3,
                                               u16* __restrict__ dst){
  int which = blockIdx.x >> 10;             // 1024 blocks per weight
  int j = (blockIdx.x & 1023) * 256 + threadIdx.x;   // float4 id in [0, 262144)
  const float* s = which == 0 ? s0 : which == 1 ? s1 : which == 2 ? s2 : s3;
  float4 f = reinterpret_cast<const float4*>(s)[j];
  ushort4 u;
  u.x = f2bf(f.x); u.y = f2bf(f.y); u.z = f2bf(f.z); u.w = f2bf(f.w);
  reinterpret_cast<ushort4*>(dst + (long)which * 1048576L)[j] = u;
}

// ---------- GEMM (R4-verified structure): C[M,N] = A[M,K]*W[N,K]^T (+bias) ----------
// SWZ=1: 1D grid 1024, XCD-chunked remap — each XCD gets 16 row-tiles x 8
// col-tiles processed ROW-major (the 8 blocks sharing an A-tile are
// temporally adjacent on one XCD -> A re-reads hit that XCD's L2).
enum { MODE_Q = 0, MODE_K = 1, MODE_V = 2, MODE_OUT = 3 };

template<int MODE, int SWZ>
__global__ __launch_bounds__(256) void gemm_bt(const u16* __restrict__ A,
                                               const u16* __restrict__ W,
                                               const float* __restrict__ bias,
                                               float* __restrict__ outF,
                                               u16* __restrict__ outB)
{
  __shared__ u16 As[128*64];
  __shared__ u16 Bs[128*64];
  const int tid  = threadIdx.x;
  const int lane = tid & 63;
  const int wm   = ((tid >> 6) >> 1) * 64;
  const int wn   = ((tid >> 6) & 1) * 64;
  long rowBase, colBase;
  if (SWZ){
    int lin = blockIdx.x;                   // 1024 blocks, 1024%8==0 (bijective)
    int xcd = lin & 7, j = lin >> 3;        // j in [0,128)
    int row = xcd * 16 + (j >> 3);          // 16 row-tiles per XCD
    int col = j & 7;                        // row-major col sweep
    rowBase = (long)row * 128;
    colBase = (long)col * 128;
  } else {
    rowBase = (long)blockIdx.x * 128;
    colBase = (long)blockIdx.y * 128;
  }

  f32x4 acc[4][4];
#pragma unroll
  for (int i = 0; i < 4; i++)
#pragma unroll
    for (int j = 0; j < 4; j++)
      acc[i][j] = (f32x4){0.f, 0.f, 0.f, 0.f};

  for (int kt = 0; kt < 16; ++kt){
    __syncthreads();
#pragma unroll
    for (int i = 0; i < 4; i++){
      int u = tid + i * 256;
      int r = u >> 3, c = u & 7;
      uint4 va = *reinterpret_cast<const uint4*>(A + (rowBase + r) * 1024 + kt * 64 + c * 8);
      uint4 vw = *reinterpret_cast<const uint4*>(W + (colBase + r) * 1024 + kt * 64 + c * 8);
      int ob = (r * 128 + c * 16) ^ ((r & 7) << 4);
      *reinterpret_cast<uint4*>(reinterpret_cast<char*>(As) + ob) = va;
      *reinterpret_cast<uint4*>(reinterpret_cast<char*>(Bs) + ob) = vw;
    }
    __syncthreads();
#pragma unroll
    for (int kk = 0; kk < 2; kk++){
      bf16x8 af[4], bfr[4];
#pragma unroll
      for (int mi = 0; mi < 4; mi++){
        int row = wm + mi * 16 + (lane & 15);
        int ob = (row * 128 + kk * 64 + (lane >> 4) * 16) ^ ((row & 7) << 4);
        af[mi] = ld_frag_lds(reinterpret_cast<const char*>(As), ob);
      }
#pragma unroll
      for (int ni = 0; ni < 4; ni++){
        int row = wn + ni * 16 + (lane & 15);
        int ob = (row * 128 + kk * 64 + (lane >> 4) * 16) ^ ((row & 7) << 4);
        bfr[ni] = ld_frag_lds(reinterpret_cast<const char*>(Bs), ob);
      }
#pragma unroll
      for (int mi = 0; mi < 4; mi++)
#pragma unroll
        for (int ni = 0; ni < 4; ni++)
          acc[mi][ni] = __builtin_amdgcn_mfma_f32_16x16x32_bf16(af[mi], bfr[ni], acc[mi][ni], 0, 0, 0);
    }
  }

#pragma unroll
  for (int mi = 0; mi < 4; mi++){
#pragma unroll
    for (int ni = 0; ni < 4; ni++){
      long gn = colBase + wn + ni * 16 + (lane & 15);
      float bb = 0.f;
      if (MODE == MODE_Q || MODE == MODE_V || MODE == MODE_OUT) bb = bias[gn];
      if (MODE == MODE_V){
        // f32 updated_v + fused bf16 transpose (vT[b,h,hd,kv])
        long gmBase = rowBase + wm + mi * 16 + ((lane >> 4) << 2);
        long b = gmBase >> 12, kv = gmBase & 4095;
        long h = gn >> 6, hd = gn & 63;
        long fidx = ((b * SH + h) * SKV + kv) * SHD + hd;
        ushort4 pk;
        float v0 = acc[mi][ni][0] + bb; outF[fidx          ] = v0; pk.x = f2bf(v0);
        float v1 = acc[mi][ni][1] + bb; outF[fidx +     SHD] = v1; pk.y = f2bf(v1);
        float v2 = acc[mi][ni][2] + bb; outF[fidx + 2 * SHD] = v2; pk.z = f2bf(v2);
        float v3 = acc[mi][ni][3] + bb; outF[fidx + 3 * SHD] = v3; pk.w = f2bf(v3);
        *reinterpret_cast<ushort4*>(outB + ((b * SH + h) * SHD + hd) * SKV + kv) = pk;
      } else {
#pragma unroll
        for (int r = 0; r < 4; r++){
          long gm = rowBase + wm + mi * 16 + ((lane >> 4) << 2) + r;
          float val = acc[mi][ni][r] + bb;
          if (MODE == MODE_OUT){
            outF[gm * 1024 + gn] = val;
          } else if (MODE == MODE_Q){
            long b = gm >> 9, s = gm & 511;
            long h = gn >> 6, hd = gn & 63;
            // fold 1/sqrt(HD)*log2e into Q: softmax runs in exp2 domain
            outB[((b * SH + h) * SS + s) * SHD + hd] = f2bf(val * QSCALE);
          } else { // MODE_K
            long b = gm >> 12, kv = gm & 4095;
            long h = gn >> 6, hd = gn & 63;
            long idx = ((b * SH + h) * SKV + kv) * SHD + hd;
            outF[idx] = val;
            outB[idx] = f2bf(val);
          }
        }
      }
    }
  }
}

// ---------- flash attention partial: QBLK=16/wave, 8 waves/block ----------
// Per wave: 16 q rows (unchanged R6 chain). 8 waves share each staged K/V
// tile -> 128 q rows per 16KB stage, halving L3 staging traffic vs 4 waves.
// Lane c=lane&15 owns q-row c; hi=lane>>4.
// S^T[kv][q]: sT[ni][r] = S[kv=16ni+4hi+r][q=c]  (base-2 log domain via QSCALE)
// O^T[hd][q]: acc[ni][r] = O[hd=16ni+4hi+r][q=c]
__global__ __launch_bounds__(512) void attn_partial(const u16* __restrict__ qb,
                                                    const u16* __restrict__ kb,
                                                    const u16* __restrict__ vTb,
                                                    u16* __restrict__ opartB,
                                                    float* __restrict__ ml){
  __shared__ u16 Klds[64 * 64];             // [kv][hd], 128B rows, swizzled
  __shared__ u16 Vlds[64 * 64];             // [hd][kv], 128B rows, swizzled
  __shared__ u16 PT[8][16 * 72];            // per-wave P^T[q][kv], stride 72 u16
  const int tid  = threadIdx.x;
  const int lane = tid & 63;
  const int wid  = tid >> 6;                // 0..7
  const int c    = lane & 15;
  const int hi   = lane >> 4;
  const long bh  = blockIdx.x;
  const int  qt  = blockIdx.y;              // q-tile of 128 rows
  const int  split = blockIdx.z;

  const u16* qp = qb + (bh * SS + qt * 128 + wid * 16 + c) * SHD + hi * 8;
  const bf16x8 bq0 = ld_frag_g(qp);
  const bf16x8 bq1 = ld_frag_g(qp + 32);

  f32x4 acc[4];
#pragma unroll
  for (int i = 0; i < 4; i++) acc[i] = (f32x4){0.f, 0.f, 0.f, 0.f};
  float mrun = -INFINITY, lrun = 0.f;

  const u16* kbase = kb  + bh * SKV * SHD;
  const u16* vbase = vTb + bh * SHD * SKV;
  u16* pt = &PT[wid][0];
  char* kch = reinterpret_cast<char*>(Klds);
  char* vch = reinterpret_cast<char*>(Vlds);

  for (int kt = split * 16; kt < split * 16 + 16; ++kt){
    __syncthreads();                        // previous tile's readers done
    {
      int u = tid;                          // [0,512): 64 rows x 8 x 16B
      int r = u >> 3, cc = u & 7;
      uint4 kv4 = *reinterpret_cast<const uint4*>(kbase + (kt * 64 + r) * SHD + cc * 8);
      uint4 vv4 = *reinterpret_cast<const uint4*>(vbase + (long)r * SKV + kt * 64 + cc * 8);
      int ob = (r * 128 + cc * 16) ^ ((r & 7) << 4);
      *reinterpret_cast<uint4*>(kch + ob) = kv4;
      *reinterpret_cast<uint4*>(vch + ob) = vv4;
    }
    __syncthreads();

    // S^T = K · Q^T : 8 MFMAs, K-frags from LDS
    f32x4 sT[4];
#pragma unroll
    for (int ni = 0; ni < 4; ni++){
      int krow = ni * 16 + c;
      int swz = (krow & 7) << 4;
      int a0 = (krow * 128 + hi * 16) ^ swz;
      int a1 = (krow * 128 + 64 + hi * 16) ^ swz;
      f32x4 z = (f32x4){0.f, 0.f, 0.f, 0.f};
      sT[ni] = __builtin_amdgcn_mfma_f32_16x16x32_bf16(ld_frag_lds(kch, a0), bq0, z, 0, 0, 0);
      sT[ni] = __builtin_amdgcn_mfma_f32_16x16x32_bf16(ld_frag_lds(kch, a1), bq1, sT[ni], 0, 0, 0);
    }
    // per-lane softmax for q-row c (base-2 domain; scale folded into Q)
    f32x4 mv = __builtin_elementwise_max(__builtin_elementwise_max(sT[0], sT[1]),
                                         __builtin_elementwise_max(sT[2], sT[3]));
    float t = fmaxf(fmaxf(mv[0], mv[1]), fmaxf(mv[2], mv[3]));
    t = fmaxf(t, __shfl_xor(t, 16));
    t = fmaxf(t, __shfl_xor(t, 32));
    float mn = fmaxf(mrun, t);
    float al = exp2f(mrun - mn);
    f32x4 psv = (f32x4){0.f, 0.f, 0.f, 0.f};
#pragma unroll
    for (int ni = 0; ni < 4; ni++){
      f32x4 p;
      p[0] = exp2f(sT[ni][0] - mn); p[1] = exp2f(sT[ni][1] - mn);
      p[2] = exp2f(sT[ni][2] - mn); p[3] = exp2f(sT[ni][3] - mn);
      psv += p;
      ushort4 pk;
      pk.x = f2bf(p[0]); pk.y = f2bf(p[1]); pk.z = f2bf(p[2]); pk.w = f2bf(p[3]);
      *reinterpret_cast<ushort4*>(pt + c * 72 + ni * 16 + hi * 4) = pk;
    }
    float ps = (psv[0] + psv[1]) + (psv[2] + psv[3]);
    ps += __shfl_xor(ps, 16);
    ps += __shfl_xor(ps, 32);
    lrun = lrun * al + ps;
    mrun = mn;
#pragma unroll
    for (int ni = 0; ni < 4; ni++) acc[ni] *= al;
    // O^T += V^T · P^T : 8 MFMAs, V-frags from LDS
#pragma unroll
    for (int m = 0; m < 2; m++){
      bf16x8 pfrag = __builtin_bit_cast(bf16x8,
          *reinterpret_cast<const uint4*>(pt + c * 72 + m * 32 + hi * 8));
#pragma unroll
      for (int ni = 0; ni < 4; ni++){
        int vrow = ni * 16 + c;
        int av = (vrow * 128 + m * 64 + hi * 16) ^ ((vrow & 7) << 4);
        acc[ni] = __builtin_amdgcn_mfma_f32_16x16x32_bf16(ld_frag_lds(vch, av), pfrag, acc[ni], 0, 0, 0);
      }
    }
  }

  // epilogue: unnormalized O^T partials (bf16) + per-row m,l (m in base-2 domain)
  const long row = bh * SS + (long)qt * 128 + wid * 16 + c;
  u16* ob = opartB + ((long)split * NROWS + row) * SHD;
#pragma unroll
  for (int ni = 0; ni < 4; ni++){
    ushort4 pk;
    pk.x = f2bf(acc[ni][0]); pk.y = f2bf(acc[ni][1]);
    pk.z = f2bf(acc[ni][2]); pk.w = f2bf(acc[ni][3]);
    *reinterpret_cast<ushort4*>(ob + ni * 16 + hi * 4) = pk;
  }
  if (hi == 0){
    ml[(long)split * NROWS + row] = mrun;
    ml[(long)NSPLIT * NROWS + (long)split * NROWS + row] = lrun;
  }
}

// ---------- combine bf16 partials -> attnb bf16 [B,S,D] (base-2 weights) ----------
__global__ __launch_bounds__(256) void attn_combine(const u16* __restrict__ opartB,
                                                    const float* __restrict__ ml,
                                                    u16* __restrict__ attnb){
  long idx4 = (long)blockIdx.x * 256 + threadIdx.x;   // ushort4 id, 16 per row
  long row = idx4 >> 4;
  int  c   = (int)(idx4 & 15);
  float m0 = ml[row], m1 = ml[NROWS + row], m2 = ml[2L*NROWS + row], m3 = ml[3L*NROWS + row];
  float M = fmaxf(fmaxf(m0, m1), fmaxf(m2, m3));
  float w0 = exp2f(m0 - M), w1 = exp2f(m1 - M), w2 = exp2f(m2 - M), w3 = exp2f(m3 - M);
  const float* lb = ml + (long)NSPLIT * NROWS;
  float L = w0*lb[row] + w1*lb[NROWS+row] + w2*lb[2L*NROWS+row] + w3*lb[3L*NROWS+row];
  float inv = 1.f / L;
  const ushort4* op = reinterpret_cast<const ushort4*>(opartB);
  ushort4 v0 = op[(0L*NROWS + row) * 16 + c];
  ushort4 v1 = op[(1L*NROWS + row) * 16 + c];
  ushort4 v2 = op[(2L*NROWS + row) * 16 + c];
  ushort4 v3 = op[(3L*NROWS + row) * 16 + c];
  float4 val;
  val.x = (w0*bf2f(v0.x) + w1*bf2f(v1.x) + w2*bf2f(v2.x) + w3*bf2f(v3.x)) * inv;
  val.y = (w0*bf2f(v0.y) + w1*bf2f(v1.y) + w2*bf2f(v2.y) + w3*bf2f(v3.y)) * inv;
  val.z = (w0*bf2f(v0.z) + w1*bf2f(v1.z) + w2*bf2f(v2.z) + w3*bf2f(v3.z)) * inv;
  val.w = (w0*bf2f(v0.w) + w1*bf2f(v1.w) + w2*bf2f(v2.w) + w3*bf2f(v3.w)) * inv;
  long bh = row >> 9, s = row & 511;
  long b = bh >> 4, h = bh & 15;
  ushort4 u;
  u.x = f2bf(val.x); u.y = f2bf(val.y); u.z = f2bf(val.z); u.w = f2bf(val.w);
  reinterpret_cast<ushort4*>(attnb)[((b * SS + s) * SD + h * SHD) / 4 + c] = u;
}

extern "C" void kernel_launch(void* const* d_in, const int* in_sizes, int n_in,
                              void* d_out, int out_size, void* d_ws, size_t ws_size,
                              hipStream_t stream)
{
  const float* x  = (const float*)d_in[0];
  const float* xa = (const float*)d_in[1];
  const float* Wq = (const float*)d_in[2];
  const float* bq = (const float*)d_in[3];
  const float* Wk = (const float*)d_in[4];
  const float* Wv = (const float*)d_in[5];
  const float* bv = (const float*)d_in[6];
  const float* Wo = (const float*)d_in[7];
  const float* bo = (const float*)d_in[8];

  float* outO = (float*)d_out;
  float* outK = outO + (long)SB * SS * SD;
  float* outV = outK + (long)SB * SH * SKV * SHD;

  u16* ws   = (u16*)d_ws;
  u16* xb   = ws;                                     // 2M u16 (reused as attnb)
  u16* xab  = xb   + 2097152L;                        // 16.7M u16 (reused as opartB)
  u16* Wqb  = xab  + 16777216L;
  u16* Wkb  = Wqb  + 1048576L;
  u16* Wvb  = Wkb  + 1048576L;
  u16* Wob  = Wvb  + 1048576L;
  u16* qbuf = Wob  + 1048576L;                        // [B,H,S,HD] bf16
  u16* kbuf = qbuf + 2097152L;                        // [B,H,KV,HD] bf16
  u16* vTbuf= kbuf + 16777216L;                       // [B,H,HD,KV] bf16
  u16* mlb  = vTbuf+ 16777216L;                       // 8*32768 f32

  u16*   attnb  = xb;                                 // alias: xb dead after gemm_Q
  u16*   opartB = xab;                                // alias: xab dead after gemm_V
  float* ml     = (float*)mlb;

  cast_kernel<<<2048, 256, 0, stream>>>(x,  xb,  524288);     // 2M f32
  cast_kernel<<<16384, 256, 0, stream>>>(xa, xab, 4194304);   // 16.7M f32
  cast_w4    <<<4096, 256, 0, stream>>>(Wq, Wk, Wv, Wo, Wqb); // 4x 1M f32

  gemm_bt<MODE_Q, 0>  <<<dim3(16, 8), 256, 0, stream>>>(xb,  Wqb, bq, nullptr, qbuf);
  gemm_bt<MODE_K, 1>  <<<1024,        256, 0, stream>>>(xab, Wkb, nullptr, outK, kbuf);
  gemm_bt<MODE_V, 1>  <<<1024,        256, 0, stream>>>(xab, Wvb, bv, outV, vTbuf);
  attn_partial        <<<dim3(64, 4, NSPLIT), 512, 0, stream>>>(qbuf, kbuf, vTbuf, opartB, ml);
  attn_combine        <<<2048, 256, 0, stream>>>(opartB, ml, attnb);
  gemm_bt<MODE_OUT, 0><<<dim3(16, 8), 256, 0, stream>>>(attnb, Wob, bo, outO, nullptr);
}

// Round 11
// 258.123 us; speedup vs baseline: 1.2804x; 1.0176x over previous
//
#include <hip/hip_runtime.h>
#include <hip/hip_bf16.h>

using u16 = unsigned short;
typedef __bf16 bf16x8 __attribute__((ext_vector_type(8)));
typedef float f32x4 __attribute__((ext_vector_type(4)));

// B=4, S=512, KV=4096, D=1024, H=16, HD=64
#define SB 4
#define SS 512
#define SKV 4096
#define SD 1024
#define SH 16
#define SHD 64
#define NSPLIT 4
#define NROWS 32768   // B*H*S
#define QSCALE 0.18033688011112042f   // 0.125 * log2(e): softmax in base-2 domain
#define DEFER_THR 6.0f                // T13: P bounded by 2^6, skip rescale

__device__ inline u16 f2bf(float f){
  __hip_bfloat16 h = __float2bfloat16(f);
  return __builtin_bit_cast(u16, h);
}
__device__ inline float bf2f(u16 u){
  return __builtin_bit_cast(float, (unsigned)u << 16);
}

__device__ inline bf16x8 ld_frag_g(const u16* p){
  uint4 v = *reinterpret_cast<const uint4*>(p);
  return __builtin_bit_cast(bf16x8, v);
}

__device__ inline bf16x8 ld_frag_lds(const char* base, int ob){
  uint4 v = *reinterpret_cast<const uint4*>(base + ob);
  return __builtin_bit_cast(bf16x8, v);
}

// pack two positive f32 into 2 truncated bf16 (1 v_perm): {hi16(b), hi16(a)}
__device__ inline unsigned pack_bf_trunc(float a, float b){
  return __builtin_amdgcn_perm(__builtin_bit_cast(unsigned, b),
                               __builtin_bit_cast(unsigned, a), 0x07060302u);
}

// ---------- f32 -> bf16 cast ----------
__global__ __launch_bounds__(256) void cast_kernel(const float* __restrict__ src,
                                                   u16* __restrict__ dst, int n4){
  int i = blockIdx.x * 256 + threadIdx.x;
  if (i < n4){
    float4 f = reinterpret_cast<const float4*>(src)[i];
    ushort4 u;
    u.x = f2bf(f.x); u.y = f2bf(f.y); u.z = f2bf(f.z); u.w = f2bf(f.w);
    reinterpret_cast<ushort4*>(dst)[i] = u;
  }
}

// 4 weight matrices (1M f32 each) in one launch; dst stride 1M u16
__global__ __launch_bounds__(256) void cast_w4(const float* __restrict__ s0,
                                               const float* __restrict__ s1,
                                               const float* __restrict__ s2,
                                               const float* __restrict__ s3,
                                               u16* __restrict__ dst){
  int which = blockIdx.x >> 10;             // 1024 blocks per weight
  int j = (blockIdx.x & 1023) * 256 + threadIdx.x;   // float4 id in [0, 262144)
  const float* s = which == 0 ? s0 : which == 1 ? s1 : which == 2 ? s2 : s3;
  float4 f = reinterpret_cast<const float4*>(s)[j];
  ushort4 u;
  u.x = f2bf(f.x); u.y = f2bf(f.y); u.z = f2bf(f.z); u.w = f2bf(f.w);
  reinterpret_cast<ushort4*>(dst + (long)which * 1048576L)[j] = u;
}

// ---------- GEMM (R4-verified structure): C[M,N] = A[M,K]*W[N,K]^T (+bias) ----------
// SWZ=1: 1D grid 1024, XCD-chunked remap — each XCD gets 16 row-tiles x 8
// col-tiles processed ROW-major (the 8 blocks sharing an A-tile are
// temporally adjacent on one XCD -> A re-reads hit that XCD's L2).
enum { MODE_Q = 0, MODE_K = 1, MODE_V = 2, MODE_OUT = 3 };

template<int MODE, int SWZ>
__global__ __launch_bounds__(256) void gemm_bt(const u16* __restrict__ A,
                                               const u16* __restrict__ W,
                                               const float* __restrict__ bias,
                                               float* __restrict__ outF,
                                               u16* __restrict__ outB)
{
  __shared__ u16 As[128*64];
  __shared__ u16 Bs[128*64];
  const int tid  = threadIdx.x;
  const int lane = tid & 63;
  const int wm   = ((tid >> 6) >> 1) * 64;
  const int wn   = ((tid >> 6) & 1) * 64;
  long rowBase, colBase;
  if (SWZ){
    int lin = blockIdx.x;                   // 1024 blocks, 1024%8==0 (bijective)
    int xcd = lin & 7, j = lin >> 3;        // j in [0,128)
    int row = xcd * 16 + (j >> 3);          // 16 row-tiles per XCD
    int col = j & 7;                        // row-major col sweep
    rowBase = (long)row * 128;
    colBase = (long)col * 128;
  } else {
    rowBase = (long)blockIdx.x * 128;
    colBase = (long)blockIdx.y * 128;
  }

  f32x4 acc[4][4];
#pragma unroll
  for (int i = 0; i < 4; i++)
#pragma unroll
    for (int j = 0; j < 4; j++)
      acc[i][j] = (f32x4){0.f, 0.f, 0.f, 0.f};

  for (int kt = 0; kt < 16; ++kt){
    __syncthreads();
#pragma unroll
    for (int i = 0; i < 4; i++){
      int u = tid + i * 256;
      int r = u >> 3, c = u & 7;
      uint4 va = *reinterpret_cast<const uint4*>(A + (rowBase + r) * 1024 + kt * 64 + c * 8);
      uint4 vw = *reinterpret_cast<const uint4*>(W + (colBase + r) * 1024 + kt * 64 + c * 8);
      int ob = (r * 128 + c * 16) ^ ((r & 7) << 4);
      *reinterpret_cast<uint4*>(reinterpret_cast<char*>(As) + ob) = va;
      *reinterpret_cast<uint4*>(reinterpret_cast<char*>(Bs) + ob) = vw;
    }
    __syncthreads();
#pragma unroll
    for (int kk = 0; kk < 2; kk++){
      bf16x8 af[4], bfr[4];
#pragma unroll
      for (int mi = 0; mi < 4; mi++){
        int row = wm + mi * 16 + (lane & 15);
        int ob = (row * 128 + kk * 64 + (lane >> 4) * 16) ^ ((row & 7) << 4);
        af[mi] = ld_frag_lds(reinterpret_cast<const char*>(As), ob);
      }
#pragma unroll
      for (int ni = 0; ni < 4; ni++){
        int row = wn + ni * 16 + (lane & 15);
        int ob = (row * 128 + kk * 64 + (lane >> 4) * 16) ^ ((row & 7) << 4);
        bfr[ni] = ld_frag_lds(reinterpret_cast<const char*>(Bs), ob);
      }
#pragma unroll
      for (int mi = 0; mi < 4; mi++)
#pragma unroll
        for (int ni = 0; ni < 4; ni++)
          acc[mi][ni] = __builtin_amdgcn_mfma_f32_16x16x32_bf16(af[mi], bfr[ni], acc[mi][ni], 0, 0, 0);
    }
  }

#pragma unroll
  for (int mi = 0; mi < 4; mi++){
#pragma unroll
    for (int ni = 0; ni < 4; ni++){
      long gn = colBase + wn + ni * 16 + (lane & 15);
      float bb = 0.f;
      if (MODE == MODE_Q || MODE == MODE_V || MODE == MODE_OUT) bb = bias[gn];
      if (MODE == MODE_V){
        // f32 updated_v + fused bf16 transpose (vT[b,h,hd,kv])
        long gmBase = rowBase + wm + mi * 16 + ((lane >> 4) << 2);
        long b = gmBase >> 12, kv = gmBase & 4095;
        long h = gn >> 6, hd = gn & 63;
        long fidx = ((b * SH + h) * SKV + kv) * SHD + hd;
        ushort4 pk;
        float v0 = acc[mi][ni][0] + bb; outF[fidx          ] = v0; pk.x = f2bf(v0);
        float v1 = acc[mi][ni][1] + bb; outF[fidx +     SHD] = v1; pk.y = f2bf(v1);
        float v2 = acc[mi][ni][2] + bb; outF[fidx + 2 * SHD] = v2; pk.z = f2bf(v2);
        float v3 = acc[mi][ni][3] + bb; outF[fidx + 3 * SHD] = v3; pk.w = f2bf(v3);
        *reinterpret_cast<ushort4*>(outB + ((b * SH + h) * SHD + hd) * SKV + kv) = pk;
      } else {
#pragma unroll
        for (int r = 0; r < 4; r++){
          long gm = rowBase + wm + mi * 16 + ((lane >> 4) << 2) + r;
          float val = acc[mi][ni][r] + bb;
          if (MODE == MODE_OUT){
            outF[gm * 1024 + gn] = val;
          } else if (MODE == MODE_Q){
            long b = gm >> 9, s = gm & 511;
            long h = gn >> 6, hd = gn & 63;
            // fold 1/sqrt(HD)*log2e into Q: softmax runs in exp2 domain
            outB[((b * SH + h) * SS + s) * SHD + hd] = f2bf(val * QSCALE);
          } else { // MODE_K
            long b = gm >> 12, kv = gm & 4095;
            long h = gn >> 6, hd = gn & 63;
            long idx = ((b * SH + h) * SKV + kv) * SHD + hd;
            outF[idx] = val;
            outB[idx] = f2bf(val);
          }
        }
      }
    }
  }
}

// ---------- flash attention partial: QBLK=16/wave, 8 waves/block ----------
// R10 structure + T13 defer-max + lane-partial l + trunc-pack P:
//  - common path has NO cross-lane shuffles, NO rescale, NO cvt ops;
//  - rescale path (wave-uniform, rare) does the full shuffle row-max.
// Lane c=lane&15 owns q-row c; hi=lane>>4.
// S^T[kv][q]: sT[ni][r] = S[kv=16ni+4hi+r][q=c]  (base-2 log domain via QSCALE)
// O^T[hd][q]: acc[ni][r] = O[hd=16ni+4hi+r][q=c]
__global__ __launch_bounds__(512) void attn_partial(const u16* __restrict__ qb,
                                                    const u16* __restrict__ kb,
                                                    const u16* __restrict__ vTb,
                                                    u16* __restrict__ opartB,
                                                    float* __restrict__ ml){
  __shared__ u16 Klds[64 * 64];             // [kv][hd], 128B rows, swizzled
  __shared__ u16 Vlds[64 * 64];             // [hd][kv], 128B rows, swizzled
  __shared__ u16 PT[8][16 * 72];            // per-wave P^T[q][kv], stride 72 u16
  const int tid  = threadIdx.x;
  const int lane = tid & 63;
  const int wid  = tid >> 6;                // 0..7
  const int c    = lane & 15;
  const int hi   = lane >> 4;
  const long bh  = blockIdx.x;
  const int  qt  = blockIdx.y;              // q-tile of 128 rows
  const int  split = blockIdx.z;

  const u16* qp = qb + (bh * SS + qt * 128 + wid * 16 + c) * SHD + hi * 8;
  const bf16x8 bq0 = ld_frag_g(qp);
  const bf16x8 bq1 = ld_frag_g(qp + 32);

  f32x4 acc[4];
#pragma unroll
  for (int i = 0; i < 4; i++) acc[i] = (f32x4){0.f, 0.f, 0.f, 0.f};
  float mrun = -INFINITY;
  f32x4 lrunv = (f32x4){0.f, 0.f, 0.f, 0.f};   // per-lane partial sum of P

  const u16* kbase = kb  + bh * SKV * SHD;
  const u16* vbase = vTb + bh * SHD * SKV;
  u16* pt = &PT[wid][0];
  char* kch = reinterpret_cast<char*>(Klds);
  char* vch = reinterpret_cast<char*>(Vlds);

  for (int kt = split * 16; kt < split * 16 + 16; ++kt){
    __syncthreads();                        // previous tile's readers done
    {
      int u = tid;                          // [0,512): 64 rows x 8 x 16B
      int r = u >> 3, cc = u & 7;
      uint4 kv4 = *reinterpret_cast<const uint4*>(kbase + (kt * 64 + r) * SHD + cc * 8);
      uint4 vv4 = *reinterpret_cast<const uint4*>(vbase + (long)r * SKV + kt * 64 + cc * 8);
      int ob = (r * 128 + cc * 16) ^ ((r & 7) << 4);
      *reinterpret_cast<uint4*>(kch + ob) = kv4;
      *reinterpret_cast<uint4*>(vch + ob) = vv4;
    }
    __syncthreads();

    // S^T = K · Q^T : 8 MFMAs, K-frags from LDS
    f32x4 sT[4];
#pragma unroll
    for (int ni = 0; ni < 4; ni++){
      int krow = ni * 16 + c;
      int swz = (krow & 7) << 4;
      int a0 = (krow * 128 + hi * 16) ^ swz;
      int a1 = (krow * 128 + 64 + hi * 16) ^ swz;
      f32x4 z = (f32x4){0.f, 0.f, 0.f, 0.f};
      sT[ni] = __builtin_amdgcn_mfma_f32_16x16x32_bf16(ld_frag_lds(kch, a0), bq0, z, 0, 0, 0);
      sT[ni] = __builtin_amdgcn_mfma_f32_16x16x32_bf16(ld_frag_lds(kch, a1), bq1, sT[ni], 0, 0, 0);
    }
    // local 16-max (no shuffles); wave-uniform defer check (T13)
    f32x4 mv = __builtin_elementwise_max(__builtin_elementwise_max(sT[0], sT[1]),
                                         __builtin_elementwise_max(sT[2], sT[3]));
    float t = fmaxf(fmaxf(mv[0], mv[1]), fmaxf(mv[2], mv[3]));
    if (!__all(t <= mrun + DEFER_THR)){
      // rescale path (rare): true row-max via shuffles, rescale state
      float tr = fmaxf(t, __shfl_xor(t, 16));
      tr = fmaxf(tr, __shfl_xor(tr, 32));
      float mn = fmaxf(mrun, tr);
      float al = exp2f(mrun - mn);          // first iter: exp2(-inf)=0
      lrunv *= al;
#pragma unroll
      for (int ni = 0; ni < 4; ni++) acc[ni] *= al;
      mrun = mn;
    }
    // P = exp2(sT - mrun)  (bounded by 2^THR); trunc-pack to bf16 via v_perm
#pragma unroll
    for (int ni = 0; ni < 4; ni++){
      f32x4 p;
      p[0] = exp2f(sT[ni][0] - mrun); p[1] = exp2f(sT[ni][1] - mrun);
      p[2] = exp2f(sT[ni][2] - mrun); p[3] = exp2f(sT[ni][3] - mrun);
      lrunv += p;
      unsigned lo = pack_bf_trunc(p[0], p[1]);
      unsigned hp = pack_bf_trunc(p[2], p[3]);
      uint2 w; w.x = lo; w.y = hp;
      *reinterpret_cast<uint2*>(pt + c * 72 + ni * 16 + hi * 4) = w;
    }
    // O^T += V^T · P^T : 8 MFMAs, V-frags from LDS
#pragma unroll
    for (int m = 0; m < 2; m++){
      bf16x8 pfrag = __builtin_bit_cast(bf16x8,
          *reinterpret_cast<const uint4*>(pt + c * 72 + m * 32 + hi * 8));
#pragma unroll
      for (int ni = 0; ni < 4; ni++){
        int vrow = ni * 16 + c;
        int av = (vrow * 128 + m * 64 + hi * 16) ^ ((vrow & 7) << 4);
        acc[ni] = __builtin_amdgcn_mfma_f32_16x16x32_bf16(ld_frag_lds(vch, av), pfrag, acc[ni], 0, 0, 0);
      }
    }
  }

  // epilogue: reduce l across the row's 4 hi-lanes (deferred from the loop)
  float l = (lrunv[0] + lrunv[1]) + (lrunv[2] + lrunv[3]);
  l += __shfl_xor(l, 16);
  l += __shfl_xor(l, 32);
  const long row = bh * SS + (long)qt * 128 + wid * 16 + c;
  u16* ob = opartB + ((long)split * NROWS + row) * SHD;
#pragma unroll
  for (int ni = 0; ni < 4; ni++){
    ushort4 pk;
    pk.x = f2bf(acc[ni][0]); pk.y = f2bf(acc[ni][1]);
    pk.z = f2bf(acc[ni][2]); pk.w = f2bf(acc[ni][3]);
    *reinterpret_cast<ushort4*>(ob + ni * 16 + hi * 4) = pk;
  }
  if (hi == 0){
    ml[(long)split * NROWS + row] = mrun;
    ml[(long)NSPLIT * NROWS + (long)split * NROWS + row] = l;
  }
}

// ---------- combine bf16 partials -> attnb bf16 [B,S,D] (base-2 weights) ----------
__global__ __launch_bounds__(256) void attn_combine(const u16* __restrict__ opartB,
                                                    const float* __restrict__ ml,
                                                    u16* __restrict__ attnb){
  long idx4 = (long)blockIdx.x * 256 + threadIdx.x;   // ushort4 id, 16 per row
  long row = idx4 >> 4;
  int  c   = (int)(idx4 & 15);
  float m0 = ml[row], m1 = ml[NROWS + row], m2 = ml[2L*NROWS + row], m3 = ml[3L*NROWS + row];
  float M = fmaxf(fmaxf(m0, m1), fmaxf(m2, m3));
  float w0 = exp2f(m0 - M), w1 = exp2f(m1 - M), w2 = exp2f(m2 - M), w3 = exp2f(m3 - M);
  const float* lb = ml + (long)NSPLIT * NROWS;
  float L = w0*lb[row] + w1*lb[NROWS+row] + w2*lb[2L*NROWS+row] + w3*lb[3L*NROWS+row];
  float inv = 1.f / L;
  const ushort4* op = reinterpret_cast<const ushort4*>(opartB);
  ushort4 v0 = op[(0L*NROWS + row) * 16 + c];
  ushort4 v1 = op[(1L*NROWS + row) * 16 + c];
  ushort4 v2 = op[(2L*NROWS + row) * 16 + c];
  ushort4 v3 = op[(3L*NROWS + row) * 16 + c];
  float4 val;
  val.x = (w0*bf2f(v0.x) + w1*bf2f(v1.x) + w2*bf2f(v2.x) + w3*bf2f(v3.x)) * inv;
  val.y = (w0*bf2f(v0.y) + w1*bf2f(v1.y) + w2*bf2f(v2.y) + w3*bf2f(v3.y)) * inv;
  val.z = (w0*bf2f(v0.z) + w1*bf2f(v1.z) + w2*bf2f(v2.z) + w3*bf2f(v3.z)) * inv;
  val.w = (w0*bf2f(v0.w) + w1*bf2f(v1.w) + w2*bf2f(v2.w) + w3*bf2f(v3.w)) * inv;
  long bh = row >> 9, s = row & 511;
  long b = bh >> 4, h = bh & 15;
  ushort4 u;
  u.x = f2bf(val.x); u.y = f2bf(val.y); u.z = f2bf(val.z); u.w = f2bf(val.w);
  reinterpret_cast<ushort4*>(attnb)[((b * SS + s) * SD + h * SHD) / 4 + c] = u;
}

extern "C" void kernel_launch(void* const* d_in, const int* in_sizes, int n_in,
                              void* d_out, int out_size, void* d_ws, size_t ws_size,
                              hipStream_t stream)
{
  const float* x  = (const float*)d_in[0];
  const float* xa = (const float*)d_in[1];
  const float* Wq = (const float*)d_in[2];
  const float* bq = (const float*)d_in[3];
  const float* Wk = (const float*)d_in[4];
  const float* Wv = (const float*)d_in[5];
  const float* bv = (const float*)d_in[6];
  const float* Wo = (const float*)d_in[7];
  const float* bo = (const float*)d_in[8];

  float* outO = (float*)d_out;
  float* outK = outO + (long)SB * SS * SD;
  float* outV = outK + (long)SB * SH * SKV * SHD;

  u16* ws   = (u16*)d_ws;
  u16* xb   = ws;                                     // 2M u16 (reused as attnb)
  u16* xab  = xb   + 2097152L;                        // 16.7M u16 (reused as opartB)
  u16* Wqb  = xab  + 16777216L;
  u16* Wkb  = Wqb  + 1048576L;
  u16* Wvb  = Wkb  + 1048576L;
  u16* Wob  = Wvb  + 1048576L;
  u16* qbuf = Wob  + 1048576L;                        // [B,H,S,HD] bf16
  u16* kbuf = qbuf + 2097152L;                        // [B,H,KV,HD] bf16
  u16* vTbuf= kbuf + 16777216L;                       // [B,H,HD,KV] bf16
  u16* mlb  = vTbuf+ 16777216L;                       // 8*32768 f32

  u16*   attnb  = xb;                                 // alias: xb dead after gemm_Q
  u16*   opartB = xab;                                // alias: xab dead after gemm_V
  float* ml     = (float*)mlb;

  cast_kernel<<<2048, 256, 0, stream>>>(x,  xb,  524288);     // 2M f32
  cast_kernel<<<16384, 256, 0, stream>>>(xa, xab, 4194304);   // 16.7M f32
  cast_w4    <<<4096, 256, 0, stream>>>(Wq, Wk, Wv, Wo, Wqb); // 4x 1M f32

  gemm_bt<MODE_Q, 0>  <<<dim3(16, 8), 256, 0, stream>>>(xb,  Wqb, bq, nullptr, qbuf);
  gemm_bt<MODE_K, 1>  <<<1024,        256, 0, stream>>>(xab, Wkb, nullptr, outK, kbuf);
  gemm_bt<MODE_V, 1>  <<<1024,        256, 0, stream>>>(xab, Wvb, bv, outV, vTbuf);
  attn_partial        <<<dim3(64, 4, NSPLIT), 512, 0, stream>>>(qbuf, kbuf, vTbuf, opartB, ml);
  attn_combine        <<<2048, 256, 0, stream>>>(opartB, ml, attnb);
  gemm_bt<MODE_OUT, 0><<<dim3(16, 8), 256, 0, stream>>>(attnb, Wob, bo, outO, nullptr);
}

// Round 12
// 254.362 us; speedup vs baseline: 1.2993x; 1.0148x over previous
//
#include <hip/hip_runtime.h>
#include <hip/hip_bf16.h>

using u16 = unsigned short;
typedef __bf16 bf16x8 __attribute__((ext_vector_type(8)));
typedef float f32x4 __attribute__((ext_vector_type(4)));

// B=4, S=512, KV=4096, D=1024, H=16, HD=64
#define SB 4
#define SS 512
#define SKV 4096
#define SD 1024
#define SH 16
#define SHD 64
#define NSPLIT 4
#define NROWS 32768   // B*H*S
#define QSCALE 0.18033688011112042f   // 0.125 * log2(e): softmax in base-2 domain
#define DEFER_THR 6.0f                // T13: P bounded by 2^6, skip rescale

__device__ inline u16 f2bf(float f){
  __hip_bfloat16 h = __float2bfloat16(f);
  return __builtin_bit_cast(u16, h);
}
__device__ inline float bf2f(u16 u){
  return __builtin_bit_cast(float, (unsigned)u << 16);
}

__device__ inline bf16x8 ld_frag_g(const u16* p){
  uint4 v = *reinterpret_cast<const uint4*>(p);
  return __builtin_bit_cast(bf16x8, v);
}

__device__ inline bf16x8 ld_frag_lds(const char* base, int ob){
  uint4 v = *reinterpret_cast<const uint4*>(base + ob);
  return __builtin_bit_cast(bf16x8, v);
}

// pack two positive f32 into 2 truncated bf16 (1 v_perm): {hi16(b), hi16(a)}
__device__ inline unsigned pack_bf_trunc(float a, float b){
  return __builtin_amdgcn_perm(__builtin_bit_cast(unsigned, b),
                               __builtin_bit_cast(unsigned, a), 0x07060302u);
}

// ---------- f32 -> bf16 cast ----------
__global__ __launch_bounds__(256) void cast_kernel(const float* __restrict__ src,
                                                   u16* __restrict__ dst, int n4){
  int i = blockIdx.x * 256 + threadIdx.x;
  if (i < n4){
    float4 f = reinterpret_cast<const float4*>(src)[i];
    ushort4 u;
    u.x = f2bf(f.x); u.y = f2bf(f.y); u.z = f2bf(f.z); u.w = f2bf(f.w);
    reinterpret_cast<ushort4*>(dst)[i] = u;
  }
}

// 4 weight matrices (1M f32 each) in one launch; dst stride 1M u16
__global__ __launch_bounds__(256) void cast_w4(const float* __restrict__ s0,
                                               const float* __restrict__ s1,
                                               const float* __restrict__ s2,
                                               const float* __restrict__ s3,
                                               u16* __restrict__ dst){
  int which = blockIdx.x >> 10;             // 1024 blocks per weight
  int j = (blockIdx.x & 1023) * 256 + threadIdx.x;   // float4 id in [0, 262144)
  const float* s = which == 0 ? s0 : which == 1 ? s1 : which == 2 ? s2 : s3;
  float4 f = reinterpret_cast<const float4*>(s)[j];
  ushort4 u;
  u.x = f2bf(f.x); u.y = f2bf(f.y); u.z = f2bf(f.z); u.w = f2bf(f.w);
  reinterpret_cast<ushort4*>(dst + (long)which * 1048576L)[j] = u;
}

// ---------- GEMM: C[M,N] = A[M,K]*W[N,K]^T (+bias) ----------
// R4-verified math/swizzle + double-buffered LDS: one barrier per K-tile,
// next-tile global loads issued before compute so their latency hides under
// the 32 MFMAs. Write target (buf cur^1) never aliases read target (buf cur).
enum { MODE_Q = 0, MODE_K = 1, MODE_V = 2, MODE_OUT = 3 };

template<int MODE, int SWZ>
__global__ __launch_bounds__(256) void gemm_bt(const u16* __restrict__ A,
                                               const u16* __restrict__ W,
                                               const float* __restrict__ bias,
                                               float* __restrict__ outF,
                                               u16* __restrict__ outB)
{
  __shared__ u16 As[2][128*64];             // 2 x 16KB
  __shared__ u16 Bs[2][128*64];
  const int tid  = threadIdx.x;
  const int lane = tid & 63;
  const int wm   = ((tid >> 6) >> 1) * 64;
  const int wn   = ((tid >> 6) & 1) * 64;
  long rowBase, colBase;
  if (SWZ){
    int lin = blockIdx.x;                   // 1024 blocks, 1024%8==0 (bijective)
    int xcd = lin & 7, j = lin >> 3;        // j in [0,128)
    int row = xcd * 16 + (j >> 3);          // 16 row-tiles per XCD
    int col = j & 7;                        // row-major col sweep
    rowBase = (long)row * 128;
    colBase = (long)col * 128;
  } else {
    rowBase = (long)blockIdx.x * 128;
    colBase = (long)blockIdx.y * 128;
  }

  f32x4 acc[4][4];
#pragma unroll
  for (int i = 0; i < 4; i++)
#pragma unroll
    for (int j = 0; j < 4; j++)
      acc[i][j] = (f32x4){0.f, 0.f, 0.f, 0.f};

  uint4 va[4], vw[4];
#pragma unroll
  for (int i = 0; i < 4; i++){
    int u = tid + i * 256;
    int r = u >> 3, c = u & 7;
    va[i] = *reinterpret_cast<const uint4*>(A + (rowBase + r) * 1024 + c * 8);
    vw[i] = *reinterpret_cast<const uint4*>(W + (colBase + r) * 1024 + c * 8);
  }
#pragma unroll
  for (int i = 0; i < 4; i++){
    int u = tid + i * 256;
    int r = u >> 3, c = u & 7;
    int ob = (r * 128 + c * 16) ^ ((r & 7) << 4);
    *reinterpret_cast<uint4*>(reinterpret_cast<char*>(As[0]) + ob) = va[i];
    *reinterpret_cast<uint4*>(reinterpret_cast<char*>(Bs[0]) + ob) = vw[i];
  }
  __syncthreads();

  int cur = 0;
  for (int kt = 0; kt < 16; ++kt){
    uint4 va2[4], vw2[4];
    if (kt < 15){                            // issue next-tile loads early
#pragma unroll
      for (int i = 0; i < 4; i++){
        int u = tid + i * 256;
        int r = u >> 3, c = u & 7;
        va2[i] = *reinterpret_cast<const uint4*>(A + (rowBase + r) * 1024 + (kt + 1) * 64 + c * 8);
        vw2[i] = *reinterpret_cast<const uint4*>(W + (colBase + r) * 1024 + (kt + 1) * 64 + c * 8);
      }
    }
    const char* ach = reinterpret_cast<const char*>(As[cur]);
    const char* bch = reinterpret_cast<const char*>(Bs[cur]);
#pragma unroll
    for (int kk = 0; kk < 2; kk++){
      bf16x8 af[4], bfr[4];
#pragma unroll
      for (int mi = 0; mi < 4; mi++){
        int row = wm + mi * 16 + (lane & 15);
        int ob = (row * 128 + kk * 64 + (lane >> 4) * 16) ^ ((row & 7) << 4);
        af[mi] = ld_frag_lds(ach, ob);
      }
#pragma unroll
      for (int ni = 0; ni < 4; ni++){
        int row = wn + ni * 16 + (lane & 15);
        int ob = (row * 128 + kk * 64 + (lane >> 4) * 16) ^ ((row & 7) << 4);
        bfr[ni] = ld_frag_lds(bch, ob);
      }
#pragma unroll
      for (int mi = 0; mi < 4; mi++)
#pragma unroll
        for (int ni = 0; ni < 4; ni++)
          acc[mi][ni] = __builtin_amdgcn_mfma_f32_16x16x32_bf16(af[mi], bfr[ni], acc[mi][ni], 0, 0, 0);
    }
    if (kt < 15){
#pragma unroll
      for (int i = 0; i < 4; i++){
        int u = tid + i * 256;
        int r = u >> 3, c = u & 7;
        int ob = (r * 128 + c * 16) ^ ((r & 7) << 4);
        *reinterpret_cast<uint4*>(reinterpret_cast<char*>(As[cur ^ 1]) + ob) = va2[i];
        *reinterpret_cast<uint4*>(reinterpret_cast<char*>(Bs[cur ^ 1]) + ob) = vw2[i];
      }
      __syncthreads();
    }
    cur ^= 1;
  }

#pragma unroll
  for (int mi = 0; mi < 4; mi++){
#pragma unroll
    for (int ni = 0; ni < 4; ni++){
      long gn = colBase + wn + ni * 16 + (lane & 15);
      float bb = 0.f;
      if (MODE == MODE_Q || MODE == MODE_V || MODE == MODE_OUT) bb = bias[gn];
      if (MODE == MODE_V){
        // f32 updated_v + fused bf16 transpose (vT[b,h,hd,kv])
        long gmBase = rowBase + wm + mi * 16 + ((lane >> 4) << 2);
        long b = gmBase >> 12, kv = gmBase & 4095;
        long h = gn >> 6, hd = gn & 63;
        long fidx = ((b * SH + h) * SKV + kv) * SHD + hd;
        ushort4 pk;
        float v0 = acc[mi][ni][0] + bb; outF[fidx          ] = v0; pk.x = f2bf(v0);
        float v1 = acc[mi][ni][1] + bb; outF[fidx +     SHD] = v1; pk.y = f2bf(v1);
        float v2 = acc[mi][ni][2] + bb; outF[fidx + 2 * SHD] = v2; pk.z = f2bf(v2);
        float v3 = acc[mi][ni][3] + bb; outF[fidx + 3 * SHD] = v3; pk.w = f2bf(v3);
        *reinterpret_cast<ushort4*>(outB + ((b * SH + h) * SHD + hd) * SKV + kv) = pk;
      } else {
#pragma unroll
        for (int r = 0; r < 4; r++){
          long gm = rowBase + wm + mi * 16 + ((lane >> 4) << 2) + r;
          float val = acc[mi][ni][r] + bb;
          if (MODE == MODE_OUT){
            outF[gm * 1024 + gn] = val;
          } else if (MODE == MODE_Q){
            long b = gm >> 9, s = gm & 511;
            long h = gn >> 6, hd = gn & 63;
            // fold 1/sqrt(HD)*log2e into Q: softmax runs in exp2 domain
            outB[((b * SH + h) * SS + s) * SHD + hd] = f2bf(val * QSCALE);
          } else { // MODE_K
            long b = gm >> 12, kv = gm & 4095;
            long h = gn >> 6, hd = gn & 63;
            long idx = ((b * SH + h) * SKV + kv) * SHD + hd;
            outF[idx] = val;
            outB[idx] = f2bf(val);
          }
        }
      }
    }
  }
}

// ---------- flash attention partial: QBLK=16/wave, 8 waves/block ----------
// R11 math (T13 defer-max, lane-partial l, trunc-pack P) + double-buffered
// K/V staging (T14): next-tile loads issued before compute, one barrier/tile.
// Lane c=lane&15 owns q-row c; hi=lane>>4.
// S^T[kv][q]: sT[ni][r] = S[kv=16ni+4hi+r][q=c]  (base-2 log domain via QSCALE)
// O^T[hd][q]: acc[ni][r] = O[hd=16ni+4hi+r][q=c]
__global__ __launch_bounds__(512) void attn_partial(const u16* __restrict__ qb,
                                                    const u16* __restrict__ kb,
                                                    const u16* __restrict__ vTb,
                                                    u16* __restrict__ opartB,
                                                    float* __restrict__ ml){
  __shared__ u16 Klds[2][64 * 64];          // [kv][hd], 128B rows, swizzled
  __shared__ u16 Vlds[2][64 * 64];          // [hd][kv], 128B rows, swizzled
  __shared__ u16 PT[8][16 * 72];            // per-wave P^T[q][kv], stride 72 u16
  const int tid  = threadIdx.x;
  const int lane = tid & 63;
  const int wid  = tid >> 6;                // 0..7
  const int c    = lane & 15;
  const int hi   = lane >> 4;
  const long bh  = blockIdx.x;
  const int  qt  = blockIdx.y;              // q-tile of 128 rows
  const int  split = blockIdx.z;

  const u16* qp = qb + (bh * SS + qt * 128 + wid * 16 + c) * SHD + hi * 8;
  const bf16x8 bq0 = ld_frag_g(qp);
  const bf16x8 bq1 = ld_frag_g(qp + 32);

  f32x4 acc[4];
#pragma unroll
  for (int i = 0; i < 4; i++) acc[i] = (f32x4){0.f, 0.f, 0.f, 0.f};
  float mrun = -INFINITY;
  f32x4 lrunv = (f32x4){0.f, 0.f, 0.f, 0.f};   // per-lane partial sum of P

  const u16* kbase = kb  + bh * SKV * SHD;
  const u16* vbase = vTb + bh * SHD * SKV;
  u16* pt = &PT[wid][0];
  const int sr  = tid >> 3;                 // staging row [0,64)
  const int scc = tid & 7;                  // staging 16B chunk
  const int sob = (sr * 128 + scc * 16) ^ ((sr & 7) << 4);
  const int t0 = split * 16;

  // prologue: stage tile t0 into buffer 0
  {
    uint4 kv4 = *reinterpret_cast<const uint4*>(kbase + (t0 * 64 + sr) * SHD + scc * 8);
    uint4 vv4 = *reinterpret_cast<const uint4*>(vbase + (long)sr * SKV + t0 * 64 + scc * 8);
    *reinterpret_cast<uint4*>(reinterpret_cast<char*>(Klds[0]) + sob) = kv4;
    *reinterpret_cast<uint4*>(reinterpret_cast<char*>(Vlds[0]) + sob) = vv4;
  }
  __syncthreads();

  int cur = 0;
  for (int kt = t0; kt < t0 + 16; ++kt){
    const bool hn = kt + 1 < t0 + 16;
    uint4 kn, vn;
    if (hn){                                // issue next-tile loads early
      kn = *reinterpret_cast<const uint4*>(kbase + ((kt + 1) * 64 + sr) * SHD + scc * 8);
      vn = *reinterpret_cast<const uint4*>(vbase + (long)sr * SKV + (kt + 1) * 64 + scc * 8);
    }
    const char* kch = reinterpret_cast<const char*>(Klds[cur]);
    const char* vch = reinterpret_cast<const char*>(Vlds[cur]);

    // S^T = K · Q^T : 8 MFMAs, K-frags from LDS
    f32x4 sT[4];
#pragma unroll
    for (int ni = 0; ni < 4; ni++){
      int krow = ni * 16 + c;
      int swz = (krow & 7) << 4;
      int a0 = (krow * 128 + hi * 16) ^ swz;
      int a1 = (krow * 128 + 64 + hi * 16) ^ swz;
      f32x4 z = (f32x4){0.f, 0.f, 0.f, 0.f};
      sT[ni] = __builtin_amdgcn_mfma_f32_16x16x32_bf16(ld_frag_lds(kch, a0), bq0, z, 0, 0, 0);
      sT[ni] = __builtin_amdgcn_mfma_f32_16x16x32_bf16(ld_frag_lds(kch, a1), bq1, sT[ni], 0, 0, 0);
    }
    // local 16-max (no shuffles); wave-uniform defer check (T13)
    f32x4 mv = __builtin_elementwise_max(__builtin_elementwise_max(sT[0], sT[1]),
                                         __builtin_elementwise_max(sT[2], sT[3]));
    float t = fmaxf(fmaxf(mv[0], mv[1]), fmaxf(mv[2], mv[3]));
    if (!__all(t <= mrun + DEFER_THR)){
      // rescale path (rare): true row-max via shuffles, rescale state
      float tr = fmaxf(t, __shfl_xor(t, 16));
      tr = fmaxf(tr, __shfl_xor(tr, 32));
      float mn = fmaxf(mrun, tr);
      float al = exp2f(mrun - mn);          // first iter: exp2(-inf)=0
      lrunv *= al;
#pragma unroll
      for (int ni = 0; ni < 4; ni++) acc[ni] *= al;
      mrun = mn;
    }
    // P = exp2(sT - mrun)  (bounded by 2^THR); trunc-pack to bf16 via v_perm
#pragma unroll
    for (int ni = 0; ni < 4; ni++){
      f32x4 p;
      p[0] = exp2f(sT[ni][0] - mrun); p[1] = exp2f(sT[ni][1] - mrun);
      p[2] = exp2f(sT[ni][2] - mrun); p[3] = exp2f(sT[ni][3] - mrun);
      lrunv += p;
      unsigned lo = pack_bf_trunc(p[0], p[1]);
      unsigned hp = pack_bf_trunc(p[2], p[3]);
      uint2 w; w.x = lo; w.y = hp;
      *reinterpret_cast<uint2*>(pt + c * 72 + ni * 16 + hi * 4) = w;
    }
    // O^T += V^T · P^T : 8 MFMAs, V-frags from LDS
#pragma unroll
    for (int m = 0; m < 2; m++){
      bf16x8 pfrag = __builtin_bit_cast(bf16x8,
          *reinterpret_cast<const uint4*>(pt + c * 72 + m * 32 + hi * 8));
#pragma unroll
      for (int ni = 0; ni < 4; ni++){
        int vrow = ni * 16 + c;
        int av = (vrow * 128 + m * 64 + hi * 16) ^ ((vrow & 7) << 4);
        acc[ni] = __builtin_amdgcn_mfma_f32_16x16x32_bf16(ld_frag_lds(vch, av), pfrag, acc[ni], 0, 0, 0);
      }
    }
    if (hn){                                // publish next tile, one barrier
      *reinterpret_cast<uint4*>(reinterpret_cast<char*>(Klds[cur ^ 1]) + sob) = kn;
      *reinterpret_cast<uint4*>(reinterpret_cast<char*>(Vlds[cur ^ 1]) + sob) = vn;
      __syncthreads();
    }
    cur ^= 1;
  }

  // epilogue: reduce l across the row's 4 hi-lanes (deferred from the loop)
  float l = (lrunv[0] + lrunv[1]) + (lrunv[2] + lrunv[3]);
  l += __shfl_xor(l, 16);
  l += __shfl_xor(l, 32);
  const long row = bh * SS + (long)qt * 128 + wid * 16 + c;
  u16* ob = opartB + ((long)split * NROWS + row) * SHD;
#pragma unroll
  for (int ni = 0; ni < 4; ni++){
    ushort4 pk;
    pk.x = f2bf(acc[ni][0]); pk.y = f2bf(acc[ni][1]);
    pk.z = f2bf(acc[ni][2]); pk.w = f2bf(acc[ni][3]);
    *reinterpret_cast<ushort4*>(ob + ni * 16 + hi * 4) = pk;
  }
  if (hi == 0){
    ml[(long)split * NROWS + row] = mrun;
    ml[(long)NSPLIT * NROWS + (long)split * NROWS + row] = l;
  }
}

// ---------- combine bf16 partials -> attnb bf16 [B,S,D] (base-2 weights) ----------
__global__ __launch_bounds__(256) void attn_combine(const u16* __restrict__ opartB,
                                                    const float* __restrict__ ml,
                                                    u16* __restrict__ attnb){
  long idx4 = (long)blockIdx.x * 256 + threadIdx.x;   // ushort4 id, 16 per row
  long row = idx4 >> 4;
  int  c   = (int)(idx4 & 15);
  float m0 = ml[row], m1 = ml[NROWS + row], m2 = ml[2L*NROWS + row], m3 = ml[3L*NROWS + row];
  float M = fmaxf(fmaxf(m0, m1), fmaxf(m2, m3));
  float w0 = exp2f(m0 - M), w1 = exp2f(m1 - M), w2 = exp2f(m2 - M), w3 = exp2f(m3 - M);
  const float* lb = ml + (long)NSPLIT * NROWS;
  float L = w0*lb[row] + w1*lb[NROWS+row] + w2*lb[2L*NROWS+row] + w3*lb[3L*NROWS+row];
  float inv = 1.f / L;
  const ushort4* op = reinterpret_cast<const ushort4*>(opartB);
  ushort4 v0 = op[(0L*NROWS + row) * 16 + c];
  ushort4 v1 = op[(1L*NROWS + row) * 16 + c];
  ushort4 v2 = op[(2L*NROWS + row) * 16 + c];
  ushort4 v3 = op[(3L*NROWS + row) * 16 + c];
  float4 val;
  val.x = (w0*bf2f(v0.x) + w1*bf2f(v1.x) + w2*bf2f(v2.x) + w3*bf2f(v3.x)) * inv;
  val.y = (w0*bf2f(v0.y) + w1*bf2f(v1.y) + w2*bf2f(v2.y) + w3*bf2f(v3.y)) * inv;
  val.z = (w0*bf2f(v0.z) + w1*bf2f(v1.z) + w2*bf2f(v2.z) + w3*bf2f(v3.z)) * inv;
  val.w = (w0*bf2f(v0.w) + w1*bf2f(v1.w) + w2*bf2f(v2.w) + w3*bf2f(v3.w)) * inv;
  long bh = row >> 9, s = row & 511;
  long b = bh >> 4, h = bh & 15;
  ushort4 u;
  u.x = f2bf(val.x); u.y = f2bf(val.y); u.z = f2bf(val.z); u.w = f2bf(val.w);
  reinterpret_cast<ushort4*>(attnb)[((b * SS + s) * SD + h * SHD) / 4 + c] = u;
}

extern "C" void kernel_launch(void* const* d_in, const int* in_sizes, int n_in,
                              void* d_out, int out_size, void* d_ws, size_t ws_size,
                              hipStream_t stream)
{
  const float* x  = (const float*)d_in[0];
  const float* xa = (const float*)d_in[1];
  const float* Wq = (const float*)d_in[2];
  const float* bq = (const float*)d_in[3];
  const float* Wk = (const float*)d_in[4];
  const float* Wv = (const float*)d_in[5];
  const float* bv = (const float*)d_in[6];
  const float* Wo = (const float*)d_in[7];
  const float* bo = (const float*)d_in[8];

  float* outO = (float*)d_out;
  float* outK = outO + (long)SB * SS * SD;
  float* outV = outK + (long)SB * SH * SKV * SHD;

  u16* ws   = (u16*)d_ws;
  u16* xb   = ws;                                     // 2M u16 (reused as attnb)
  u16* xab  = xb   + 2097152L;                        // 16.7M u16 (reused as opartB)
  u16* Wqb  = xab  + 16777216L;
  u16* Wkb  = Wqb  + 1048576L;
  u16* Wvb  = Wkb  + 1048576L;
  u16* Wob  = Wvb  + 1048576L;
  u16* qbuf = Wob  + 1048576L;                        // [B,H,S,HD] bf16
  u16* kbuf = qbuf + 2097152L;                        // [B,H,KV,HD] bf16
  u16* vTbuf= kbuf + 16777216L;                       // [B,H,HD,KV] bf16
  u16* mlb  = vTbuf+ 16777216L;                       // 8*32768 f32

  u16*   attnb  = xb;                                 // alias: xb dead after gemm_Q
  u16*   opartB = xab;                                // alias: xab dead after gemm_V
  float* ml     = (float*)mlb;

  cast_kernel<<<2048, 256, 0, stream>>>(x,  xb,  524288);     // 2M f32
  cast_kernel<<<16384, 256, 0, stream>>>(xa, xab, 4194304);   // 16.7M f32
  cast_w4    <<<4096, 256, 0, stream>>>(Wq, Wk, Wv, Wo, Wqb); // 4x 1M f32

  gemm_bt<MODE_Q, 0>  <<<dim3(16, 8), 256, 0, stream>>>(xb,  Wqb, bq, nullptr, qbuf);
  gemm_bt<MODE_K, 1>  <<<1024,        256, 0, stream>>>(xab, Wkb, nullptr, outK, kbuf);
  gemm_bt<MODE_V, 1>  <<<1024,        256, 0, stream>>>(xab, Wvb, bv, outV, vTbuf);
  attn_partial        <<<dim3(64, 4, NSPLIT), 512, 0, stream>>>(qbuf, kbuf, vTbuf, opartB, ml);
  attn_combine        <<<2048, 256, 0, stream>>>(opartB, ml, attnb);
  gemm_bt<MODE_OUT, 0><<<dim3(16, 8), 256, 0, stream>>>(attnb, Wob, bo, outO, nullptr);
}

// Round 13
// 254.330 us; speedup vs baseline: 1.2995x; 1.0001x over previous
//
#include <hip/hip_runtime.h>
#include <hip/hip_bf16.h>

using u16 = unsigned short;
typedef __bf16 bf16x8 __attribute__((ext_vector_type(8)));
typedef float f32x4 __attribute__((ext_vector_type(4)));

// B=4, S=512, KV=4096, D=1024, H=16, HD=64
#define SB 4
#define SS 512
#define SKV 4096
#define SD 1024
#define SH 16
#define SHD 64
#define NSPLIT 4
#define NROWS 32768   // B*H*S
#define QSCALE 0.18033688011112042f   // 0.125 * log2(e): softmax in base-2 domain
#define DEFER_THR 6.0f                // T13: P bounded by 2^6, skip rescale

__device__ inline u16 f2bf(float f){
  __hip_bfloat16 h = __float2bfloat16(f);
  return __builtin_bit_cast(u16, h);
}
__device__ inline float bf2f(u16 u){
  return __builtin_bit_cast(float, (unsigned)u << 16);
}

__device__ inline bf16x8 ld_frag_g(const u16* p){
  uint4 v = *reinterpret_cast<const uint4*>(p);
  return __builtin_bit_cast(bf16x8, v);
}

__device__ inline bf16x8 ld_frag_lds(const char* base, int ob){
  uint4 v = *reinterpret_cast<const uint4*>(base + ob);
  return __builtin_bit_cast(bf16x8, v);
}

// pack two positive f32 into 2 truncated bf16 (1 v_perm): {hi16(b), hi16(a)}
__device__ inline unsigned pack_bf_trunc(float a, float b){
  return __builtin_amdgcn_perm(__builtin_bit_cast(unsigned, b),
                               __builtin_bit_cast(unsigned, a), 0x07060302u);
}

// ---------- f32 -> bf16 cast ----------
__global__ __launch_bounds__(256) void cast_kernel(const float* __restrict__ src,
                                                   u16* __restrict__ dst, int n4){
  int i = blockIdx.x * 256 + threadIdx.x;
  if (i < n4){
    float4 f = reinterpret_cast<const float4*>(src)[i];
    ushort4 u;
    u.x = f2bf(f.x); u.y = f2bf(f.y); u.z = f2bf(f.z); u.w = f2bf(f.w);
    reinterpret_cast<ushort4*>(dst)[i] = u;
  }
}

// 4 weight matrices (1M f32 each) in one launch; dst stride 1M u16
__global__ __launch_bounds__(256) void cast_w4(const float* __restrict__ s0,
                                               const float* __restrict__ s1,
                                               const float* __restrict__ s2,
                                               const float* __restrict__ s3,
                                               u16* __restrict__ dst){
  int which = blockIdx.x >> 10;             // 1024 blocks per weight
  int j = (blockIdx.x & 1023) * 256 + threadIdx.x;   // float4 id in [0, 262144)
  const float* s = which == 0 ? s0 : which == 1 ? s1 : which == 2 ? s2 : s3;
  float4 f = reinterpret_cast<const float4*>(s)[j];
  ushort4 u;
  u.x = f2bf(f.x); u.y = f2bf(f.y); u.z = f2bf(f.z); u.w = f2bf(f.w);
  reinterpret_cast<ushort4*>(dst + (long)which * 1048576L)[j] = u;
}

enum { MODE_Q = 0, MODE_K = 1, MODE_V = 2, MODE_OUT = 3 };

// ---------- 128^2 GEMM (R12-verified dbuf) for small-M Q/OUT ----------
template<int MODE>
__global__ __launch_bounds__(256) void gemm_bt(const u16* __restrict__ A,
                                               const u16* __restrict__ W,
                                               const float* __restrict__ bias,
                                               float* __restrict__ outF,
                                               u16* __restrict__ outB)
{
  __shared__ u16 As[2][128*64];
  __shared__ u16 Bs[2][128*64];
  const int tid  = threadIdx.x;
  const int lane = tid & 63;
  const int wm   = ((tid >> 6) >> 1) * 64;
  const int wn   = ((tid >> 6) & 1) * 64;
  const long rowBase = (long)blockIdx.x * 128;
  const long colBase = (long)blockIdx.y * 128;

  f32x4 acc[4][4];
#pragma unroll
  for (int i = 0; i < 4; i++)
#pragma unroll
    for (int j = 0; j < 4; j++)
      acc[i][j] = (f32x4){0.f, 0.f, 0.f, 0.f};

  uint4 va[4], vw[4];
#pragma unroll
  for (int i = 0; i < 4; i++){
    int u = tid + i * 256;
    int r = u >> 3, c = u & 7;
    va[i] = *reinterpret_cast<const uint4*>(A + (rowBase + r) * 1024 + c * 8);
    vw[i] = *reinterpret_cast<const uint4*>(W + (colBase + r) * 1024 + c * 8);
  }
#pragma unroll
  for (int i = 0; i < 4; i++){
    int u = tid + i * 256;
    int r = u >> 3, c = u & 7;
    int ob = (r * 128 + c * 16) ^ ((r & 7) << 4);
    *reinterpret_cast<uint4*>(reinterpret_cast<char*>(As[0]) + ob) = va[i];
    *reinterpret_cast<uint4*>(reinterpret_cast<char*>(Bs[0]) + ob) = vw[i];
  }
  __syncthreads();

  int cur = 0;
  for (int kt = 0; kt < 16; ++kt){
    uint4 va2[4], vw2[4];
    if (kt < 15){
#pragma unroll
      for (int i = 0; i < 4; i++){
        int u = tid + i * 256;
        int r = u >> 3, c = u & 7;
        va2[i] = *reinterpret_cast<const uint4*>(A + (rowBase + r) * 1024 + (kt + 1) * 64 + c * 8);
        vw2[i] = *reinterpret_cast<const uint4*>(W + (colBase + r) * 1024 + (kt + 1) * 64 + c * 8);
      }
    }
    const char* ach = reinterpret_cast<const char*>(As[cur]);
    const char* bch = reinterpret_cast<const char*>(Bs[cur]);
#pragma unroll
    for (int kk = 0; kk < 2; kk++){
      bf16x8 af[4], bfr[4];
#pragma unroll
      for (int mi = 0; mi < 4; mi++){
        int row = wm + mi * 16 + (lane & 15);
        int ob = (row * 128 + kk * 64 + (lane >> 4) * 16) ^ ((row & 7) << 4);
        af[mi] = ld_frag_lds(ach, ob);
      }
#pragma unroll
      for (int ni = 0; ni < 4; ni++){
        int row = wn + ni * 16 + (lane & 15);
        int ob = (row * 128 + kk * 64 + (lane >> 4) * 16) ^ ((row & 7) << 4);
        bfr[ni] = ld_frag_lds(bch, ob);
      }
#pragma unroll
      for (int mi = 0; mi < 4; mi++)
#pragma unroll
        for (int ni = 0; ni < 4; ni++)
          acc[mi][ni] = __builtin_amdgcn_mfma_f32_16x16x32_bf16(af[mi], bfr[ni], acc[mi][ni], 0, 0, 0);
    }
    if (kt < 15){
#pragma unroll
      for (int i = 0; i < 4; i++){
        int u = tid + i * 256;
        int r = u >> 3, c = u & 7;
        int ob = (r * 128 + c * 16) ^ ((r & 7) << 4);
        *reinterpret_cast<uint4*>(reinterpret_cast<char*>(As[cur ^ 1]) + ob) = va2[i];
        *reinterpret_cast<uint4*>(reinterpret_cast<char*>(Bs[cur ^ 1]) + ob) = vw2[i];
      }
      __syncthreads();
    }
    cur ^= 1;
  }

#pragma unroll
  for (int mi = 0; mi < 4; mi++){
#pragma unroll
    for (int ni = 0; ni < 4; ni++){
      long gn = colBase + wn + ni * 16 + (lane & 15);
      float bb = bias[gn];
#pragma unroll
      for (int r = 0; r < 4; r++){
        long gm = rowBase + wm + mi * 16 + ((lane >> 4) << 2) + r;
        float val = acc[mi][ni][r] + bb;
        if (MODE == MODE_OUT){
          outF[gm * 1024 + gn] = val;
        } else { // MODE_Q: fold 1/sqrt(HD)*log2e
          long b = gm >> 9, s = gm & 511;
          long h = gn >> 6, hd = gn & 63;
          outB[((b * SH + h) * SS + s) * SHD + hd] = f2bf(val * QSCALE);
        }
      }
    }
  }
}

// ---------- 256^2 GEMM (dbuf, 8 waves) for K/V: M=16384, N=1024, K=1024 ----------
// Per staged 64KB K-step: 8 waves x 64 MFMA = 512 MFMA (2x the 128^2 ratio).
// XCD-chunked: 256 blocks, each XCD owns 8 row-tiles x 4 cols row-major.
template<int MODE>
__global__ __launch_bounds__(512) void gemm_bt256(const u16* __restrict__ A,
                                                  const u16* __restrict__ W,
                                                  const float* __restrict__ bias,
                                                  float* __restrict__ outF,
                                                  u16* __restrict__ outB)
{
  __shared__ u16 As[2][256*64];             // 2 x 32KB
  __shared__ u16 Bs[2][256*64];
  const int tid  = threadIdx.x;
  const int lane = tid & 63;
  const int wid  = tid >> 6;                // 0..7
  const int wm   = (wid >> 2) * 128;        // 2 M-groups
  const int wn   = (wid & 3) * 64;          // 4 N-groups
  int lin = blockIdx.x;                     // 256 blocks, 256%8==0 (bijective)
  int xcd = lin & 7, j = lin >> 3;          // j in [0,32)
  const long rowBase = (long)(xcd * 8 + (j >> 2)) * 256;
  const long colBase = (long)(j & 3) * 256;

  f32x4 acc[8][4];
#pragma unroll
  for (int i = 0; i < 8; i++)
#pragma unroll
    for (int jj = 0; jj < 4; jj++)
      acc[i][jj] = (f32x4){0.f, 0.f, 0.f, 0.f};

  uint4 va[4], vw[4];
#pragma unroll
  for (int i = 0; i < 4; i++){
    int u = tid + i * 512;                  // [0,2048): 256 rows x 8 chunks
    int r = u >> 3, c = u & 7;
    va[i] = *reinterpret_cast<const uint4*>(A + (rowBase + r) * 1024 + c * 8);
    vw[i] = *reinterpret_cast<const uint4*>(W + (colBase + r) * 1024 + c * 8);
  }
#pragma unroll
  for (int i = 0; i < 4; i++){
    int u = tid + i * 512;
    int r = u >> 3, c = u & 7;
    int ob = (r * 128 + c * 16) ^ ((r & 7) << 4);
    *reinterpret_cast<uint4*>(reinterpret_cast<char*>(As[0]) + ob) = va[i];
    *reinterpret_cast<uint4*>(reinterpret_cast<char*>(Bs[0]) + ob) = vw[i];
  }
  __syncthreads();

  int cur = 0;
  for (int kt = 0; kt < 16; ++kt){
    uint4 va2[4], vw2[4];
    if (kt < 15){
#pragma unroll
      for (int i = 0; i < 4; i++){
        int u = tid + i * 512;
        int r = u >> 3, c = u & 7;
        va2[i] = *reinterpret_cast<const uint4*>(A + (rowBase + r) * 1024 + (kt + 1) * 64 + c * 8);
        vw2[i] = *reinterpret_cast<const uint4*>(W + (colBase + r) * 1024 + (kt + 1) * 64 + c * 8);
      }
    }
    const char* ach = reinterpret_cast<const char*>(As[cur]);
    const char* bch = reinterpret_cast<const char*>(Bs[cur]);
#pragma unroll
    for (int kk = 0; kk < 2; kk++){
      bf16x8 af[8], bfr[4];
#pragma unroll
      for (int mi = 0; mi < 8; mi++){
        int row = wm + mi * 16 + (lane & 15);
        int ob = (row * 128 + kk * 64 + (lane >> 4) * 16) ^ ((row & 7) << 4);
        af[mi] = ld_frag_lds(ach, ob);
      }
#pragma unroll
      for (int ni = 0; ni < 4; ni++){
        int row = wn + ni * 16 + (lane & 15);
        int ob = (row * 128 + kk * 64 + (lane >> 4) * 16) ^ ((row & 7) << 4);
        bfr[ni] = ld_frag_lds(bch, ob);
      }
#pragma unroll
      for (int mi = 0; mi < 8; mi++)
#pragma unroll
        for (int ni = 0; ni < 4; ni++)
          acc[mi][ni] = __builtin_amdgcn_mfma_f32_16x16x32_bf16(af[mi], bfr[ni], acc[mi][ni], 0, 0, 0);
    }
    if (kt < 15){
#pragma unroll
      for (int i = 0; i < 4; i++){
        int u = tid + i * 512;
        int r = u >> 3, c = u & 7;
        int ob = (r * 128 + c * 16) ^ ((r & 7) << 4);
        *reinterpret_cast<uint4*>(reinterpret_cast<char*>(As[cur ^ 1]) + ob) = va2[i];
        *reinterpret_cast<uint4*>(reinterpret_cast<char*>(Bs[cur ^ 1]) + ob) = vw2[i];
      }
      __syncthreads();
    }
    cur ^= 1;
  }

#pragma unroll
  for (int mi = 0; mi < 8; mi++){
#pragma unroll
    for (int ni = 0; ni < 4; ni++){
      long gn = colBase + wn + ni * 16 + (lane & 15);
      long h = gn >> 6, hd = gn & 63;
      if (MODE == MODE_V){
        float bb = bias[gn];
        long gmBase = rowBase + wm + mi * 16 + ((lane >> 4) << 2);
        long b = gmBase >> 12, kv = gmBase & 4095;
        long fidx = ((b * SH + h) * SKV + kv) * SHD + hd;
        ushort4 pk;
        float v0 = acc[mi][ni][0] + bb; outF[fidx          ] = v0; pk.x = f2bf(v0);
        float v1 = acc[mi][ni][1] + bb; outF[fidx +     SHD] = v1; pk.y = f2bf(v1);
        float v2 = acc[mi][ni][2] + bb; outF[fidx + 2 * SHD] = v2; pk.z = f2bf(v2);
        float v3 = acc[mi][ni][3] + bb; outF[fidx + 3 * SHD] = v3; pk.w = f2bf(v3);
        *reinterpret_cast<ushort4*>(outB + ((b * SH + h) * SHD + hd) * SKV + kv) = pk;
      } else { // MODE_K (no bias)
#pragma unroll
        for (int r = 0; r < 4; r++){
          long gm = rowBase + wm + mi * 16 + ((lane >> 4) << 2) + r;
          long b = gm >> 12, kv = gm & 4095;
          long idx = ((b * SH + h) * SKV + kv) * SHD + hd;
          float val = acc[mi][ni][r];
          outF[idx] = val;
          outB[idx] = f2bf(val);
        }
      }
    }
  }
}

// ---------- flash attention partial (R12-verified, unchanged) ----------
__global__ __launch_bounds__(512) void attn_partial(const u16* __restrict__ qb,
                                                    const u16* __restrict__ kb,
                                                    const u16* __restrict__ vTb,
                                                    u16* __restrict__ opartB,
                                                    float* __restrict__ ml){
  __shared__ u16 Klds[2][64 * 64];
  __shared__ u16 Vlds[2][64 * 64];
  __shared__ u16 PT[8][16 * 72];
  const int tid  = threadIdx.x;
  const int lane = tid & 63;
  const int wid  = tid >> 6;
  const int c    = lane & 15;
  const int hi   = lane >> 4;
  const long bh  = blockIdx.x;
  const int  qt  = blockIdx.y;
  const int  split = blockIdx.z;

  const u16* qp = qb + (bh * SS + qt * 128 + wid * 16 + c) * SHD + hi * 8;
  const bf16x8 bq0 = ld_frag_g(qp);
  const bf16x8 bq1 = ld_frag_g(qp + 32);

  f32x4 acc[4];
#pragma unroll
  for (int i = 0; i < 4; i++) acc[i] = (f32x4){0.f, 0.f, 0.f, 0.f};
  float mrun = -INFINITY;
  f32x4 lrunv = (f32x4){0.f, 0.f, 0.f, 0.f};

  const u16* kbase = kb  + bh * SKV * SHD;
  const u16* vbase = vTb + bh * SHD * SKV;
  u16* pt = &PT[wid][0];
  const int sr  = tid >> 3;
  const int scc = tid & 7;
  const int sob = (sr * 128 + scc * 16) ^ ((sr & 7) << 4);
  const int t0 = split * 16;

  {
    uint4 kv4 = *reinterpret_cast<const uint4*>(kbase + (t0 * 64 + sr) * SHD + scc * 8);
    uint4 vv4 = *reinterpret_cast<const uint4*>(vbase + (long)sr * SKV + t0 * 64 + scc * 8);
    *reinterpret_cast<uint4*>(reinterpret_cast<char*>(Klds[0]) + sob) = kv4;
    *reinterpret_cast<uint4*>(reinterpret_cast<char*>(Vlds[0]) + sob) = vv4;
  }
  __syncthreads();

  int cur = 0;
  for (int kt = t0; kt < t0 + 16; ++kt){
    const bool hn = kt + 1 < t0 + 16;
    uint4 kn, vn;
    if (hn){
      kn = *reinterpret_cast<const uint4*>(kbase + ((kt + 1) * 64 + sr) * SHD + scc * 8);
      vn = *reinterpret_cast<const uint4*>(vbase + (long)sr * SKV + (kt + 1) * 64 + scc * 8);
    }
    const char* kch = reinterpret_cast<const char*>(Klds[cur]);
    const char* vch = reinterpret_cast<const char*>(Vlds[cur]);

    f32x4 sT[4];
#pragma unroll
    for (int ni = 0; ni < 4; ni++){
      int krow = ni * 16 + c;
      int swz = (krow & 7) << 4;
      int a0 = (krow * 128 + hi * 16) ^ swz;
      int a1 = (krow * 128 + 64 + hi * 16) ^ swz;
      f32x4 z = (f32x4){0.f, 0.f, 0.f, 0.f};
      sT[ni] = __builtin_amdgcn_mfma_f32_16x16x32_bf16(ld_frag_lds(kch, a0), bq0, z, 0, 0, 0);
      sT[ni] = __builtin_amdgcn_mfma_f32_16x16x32_bf16(ld_frag_lds(kch, a1), bq1, sT[ni], 0, 0, 0);
    }
    f32x4 mv = __builtin_elementwise_max(__builtin_elementwise_max(sT[0], sT[1]),
                                         __builtin_elementwise_max(sT[2], sT[3]));
    float t = fmaxf(fmaxf(mv[0], mv[1]), fmaxf(mv[2], mv[3]));
    if (!__all(t <= mrun + DEFER_THR)){
      float tr = fmaxf(t, __shfl_xor(t, 16));
      tr = fmaxf(tr, __shfl_xor(tr, 32));
      float mn = fmaxf(mrun, tr);
      float al = exp2f(mrun - mn);
      lrunv *= al;
#pragma unroll
      for (int ni = 0; ni < 4; ni++) acc[ni] *= al;
      mrun = mn;
    }
#pragma unroll
    for (int ni = 0; ni < 4; ni++){
      f32x4 p;
      p[0] = exp2f(sT[ni][0] - mrun); p[1] = exp2f(sT[ni][1] - mrun);
      p[2] = exp2f(sT[ni][2] - mrun); p[3] = exp2f(sT[ni][3] - mrun);
      lrunv += p;
      unsigned lo = pack_bf_trunc(p[0], p[1]);
      unsigned hp = pack_bf_trunc(p[2], p[3]);
      uint2 w; w.x = lo; w.y = hp;
      *reinterpret_cast<uint2*>(pt + c * 72 + ni * 16 + hi * 4) = w;
    }
#pragma unroll
    for (int m = 0; m < 2; m++){
      bf16x8 pfrag = __builtin_bit_cast(bf16x8,
          *reinterpret_cast<const uint4*>(pt + c * 72 + m * 32 + hi * 8));
#pragma unroll
      for (int ni = 0; ni < 4; ni++){
        int vrow = ni * 16 + c;
        int av = (vrow * 128 + m * 64 + hi * 16) ^ ((vrow & 7) << 4);
        acc[ni] = __builtin_amdgcn_mfma_f32_16x16x32_bf16(ld_frag_lds(vch, av), pfrag, acc[ni], 0, 0, 0);
      }
    }
    if (hn){
      *reinterpret_cast<uint4*>(reinterpret_cast<char*>(Klds[cur ^ 1]) + sob) = kn;
      *reinterpret_cast<uint4*>(reinterpret_cast<char*>(Vlds[cur ^ 1]) + sob) = vn;
      __syncthreads();
    }
    cur ^= 1;
  }

  float l = (lrunv[0] + lrunv[1]) + (lrunv[2] + lrunv[3]);
  l += __shfl_xor(l, 16);
  l += __shfl_xor(l, 32);
  const long row = bh * SS + (long)qt * 128 + wid * 16 + c;
  u16* ob = opartB + ((long)split * NROWS + row) * SHD;
#pragma unroll
  for (int ni = 0; ni < 4; ni++){
    ushort4 pk;
    pk.x = f2bf(acc[ni][0]); pk.y = f2bf(acc[ni][1]);
    pk.z = f2bf(acc[ni][2]); pk.w = f2bf(acc[ni][3]);
    *reinterpret_cast<ushort4*>(ob + ni * 16 + hi * 4) = pk;
  }
  if (hi == 0){
    ml[(long)split * NROWS + row] = mrun;
    ml[(long)NSPLIT * NROWS + (long)split * NROWS + row] = l;
  }
}

// ---------- combine bf16 partials -> attnb bf16 [B,S,D] (base-2 weights) ----------
__global__ __launch_bounds__(256) void attn_combine(const u16* __restrict__ opartB,
                                                    const float* __restrict__ ml,
                                                    u16* __restrict__ attnb){
  long idx4 = (long)blockIdx.x * 256 + threadIdx.x;
  long row = idx4 >> 4;
  int  c   = (int)(idx4 & 15);
  float m0 = ml[row], m1 = ml[NROWS + row], m2 = ml[2L*NROWS + row], m3 = ml[3L*NROWS + row];
  float M = fmaxf(fmaxf(m0, m1), fmaxf(m2, m3));
  float w0 = exp2f(m0 - M), w1 = exp2f(m1 - M), w2 = exp2f(m2 - M), w3 = exp2f(m3 - M);
  const float* lb = ml + (long)NSPLIT * NROWS;
  float L = w0*lb[row] + w1*lb[NROWS+row] + w2*lb[2L*NROWS+row] + w3*lb[3L*NROWS+row];
  float inv = 1.f / L;
  const ushort4* op = reinterpret_cast<const ushort4*>(opartB);
  ushort4 v0 = op[(0L*NROWS + row) * 16 + c];
  ushort4 v1 = op[(1L*NROWS + row) * 16 + c];
  ushort4 v2 = op[(2L*NROWS + row) * 16 + c];
  ushort4 v3 = op[(3L*NROWS + row) * 16 + c];
  float4 val;
  val.x = (w0*bf2f(v0.x) + w1*bf2f(v1.x) + w2*bf2f(v2.x) + w3*bf2f(v3.x)) * inv;
  val.y = (w0*bf2f(v0.y) + w1*bf2f(v1.y) + w2*bf2f(v2.y) + w3*bf2f(v3.y)) * inv;
  val.z = (w0*bf2f(v0.z) + w1*bf2f(v1.z) + w2*bf2f(v2.z) + w3*bf2f(v3.z)) * inv;
  val.w = (w0*bf2f(v0.w) + w1*bf2f(v1.w) + w2*bf2f(v2.w) + w3*bf2f(v3.w)) * inv;
  long bh = row >> 9, s = row & 511;
  long b = bh >> 4, h = bh & 15;
  ushort4 u;
  u.x = f2bf(val.x); u.y = f2bf(val.y); u.z = f2bf(val.z); u.w = f2bf(val.w);
  reinterpret_cast<ushort4*>(attnb)[((b * SS + s) * SD + h * SHD) / 4 + c] = u;
}

extern "C" void kernel_launch(void* const* d_in, const int* in_sizes, int n_in,
                              void* d_out, int out_size, void* d_ws, size_t ws_size,
                              hipStream_t stream)
{
  const float* x  = (const float*)d_in[0];
  const float* xa = (const float*)d_in[1];
  const float* Wq = (const float*)d_in[2];
  const float* bq = (const float*)d_in[3];
  const float* Wk = (const float*)d_in[4];
  const float* Wv = (const float*)d_in[5];
  const float* bv = (const float*)d_in[6];
  const float* Wo = (const float*)d_in[7];
  const float* bo = (const float*)d_in[8];

  float* outO = (float*)d_out;
  float* outK = outO + (long)SB * SS * SD;
  float* outV = outK + (long)SB * SH * SKV * SHD;

  u16* ws   = (u16*)d_ws;
  u16* xb   = ws;                                     // 2M u16 (reused as attnb)
  u16* xab  = xb   + 2097152L;                        // 16.7M u16 (reused as opartB)
  u16* Wqb  = xab  + 16777216L;
  u16* Wkb  = Wqb  + 1048576L;
  u16* Wvb  = Wkb  + 1048576L;
  u16* Wob  = Wvb  + 1048576L;
  u16* qbuf = Wob  + 1048576L;                        // [B,H,S,HD] bf16
  u16* kbuf = qbuf + 2097152L;                        // [B,H,KV,HD] bf16
  u16* vTbuf= kbuf + 16777216L;                       // [B,H,HD,KV] bf16
  u16* mlb  = vTbuf+ 16777216L;                       // 8*32768 f32

  u16*   attnb  = xb;                                 // alias: xb dead after gemm_Q
  u16*   opartB = xab;                                // alias: xab dead after gemm_V
  float* ml     = (float*)mlb;

  cast_kernel<<<2048, 256, 0, stream>>>(x,  xb,  524288);     // 2M f32
  cast_kernel<<<16384, 256, 0, stream>>>(xa, xab, 4194304);   // 16.7M f32
  cast_w4    <<<4096, 256, 0, stream>>>(Wq, Wk, Wv, Wo, Wqb); // 4x 1M f32

  gemm_bt<MODE_Q>     <<<dim3(16, 8), 256, 0, stream>>>(xb,  Wqb, bq, nullptr, qbuf);
  gemm_bt256<MODE_K>  <<<256,         512, 0, stream>>>(xab, Wkb, nullptr, outK, kbuf);
  gemm_bt256<MODE_V>  <<<256,         512, 0, stream>>>(xab, Wvb, bv, outV, vTbuf);
  attn_partial        <<<dim3(64, 4, NSPLIT), 512, 0, stream>>>(qbuf, kbuf, vTbuf, opartB, ml);
  attn_combine        <<<2048, 256, 0, stream>>>(opartB, ml, attnb);
  gemm_bt<MODE_OUT>   <<<dim3(16, 8), 256, 0, stream>>>(attnb, Wob, bo, outO, nullptr);
}